// Round 1
// baseline (800.347 us; speedup 1.0000x reference)
//
#include <hip/hip_runtime.h>
#include <math.h>

#define HW 4096
typedef short short8 __attribute__((ext_vector_type(8)));
typedef float floatx4 __attribute__((ext_vector_type(4)));

// ---- ws layout (bytes) ----
#define O_XBT   0ull            // [8][4096][512] bf16 x NHWC
#define O_PXB   33554432ull     // [8][4096][512] bf16 pooled x NHWC (reused later)
#define O_CATB  67108864ull     // [8][4096][512] bf16 cat branches NHWC
#define O_WPB   100663296ull    // [384][512] bf16
#define O_W4B   101056512ull    // [128][512] bf16
#define O_WCCB  101187584ull    // [512][512] bf16
#define O_WD2T  101711872ull    // [9][128][128] bf16 (t,o,c)
#define O_WD3T  102006784ull    // [25][128][128] bf16 (t,o,c)
#define O_WO2T  102825984ull    // [9][64][128] bf16 (t,o,c)
#define O_WO3T  102973440ull    // [25][64][128] bf16 (t,o,c)
// reuse of PXB region after b4 GEMM:
#define O_T2B   33554432ull     // [8][4096][128] bf16 b2i NHWC
#define O_T3B   41943040ull     // [8][4096][128] bf16 b3i NHWC
#define O_OFF2  50331648ull     // [8][18][4096] f32
#define O_OFF3  52690944ull     // [8][50][4096] f32

__device__ __forceinline__ unsigned short f2b(float f) {
    union { float f; unsigned u; } v; v.f = f;
    unsigned r = v.u + 0x7FFFu + ((v.u >> 16) & 1u);
    return (unsigned short)(r >> 16);
}
__device__ __forceinline__ float lou(unsigned u) {
    union { unsigned u; float f; } v; v.u = u << 16; return v.f;
}
__device__ __forceinline__ float hiu(unsigned u) {
    union { unsigned u; float f; } v; v.u = u & 0xFFFF0000u; return v.f;
}
__device__ __forceinline__ unsigned pk2(float lo, float hi) {
    return (unsigned)f2b(lo) | ((unsigned)f2b(hi) << 16);
}

// ------------------------------------------------------------- weight prep
__global__ __launch_bounds__(256) void k_prepw(
        const float* __restrict__ w1, const float* __restrict__ w21,
        const float* __restrict__ w31, const float* __restrict__ w4,
        const float* __restrict__ wcc, const float* __restrict__ wd2,
        const float* __restrict__ wd3, const float* __restrict__ wo2,
        const float* __restrict__ wo3, unsigned short* __restrict__ ws8) {
    unsigned i = blockIdx.x * 256 + threadIdx.x;
    unsigned short* wpb  = ws8 + (O_WPB  >> 1);
    unsigned short* w4b  = ws8 + (O_W4B  >> 1);
    unsigned short* wccb = ws8 + (O_WCCB >> 1);
    unsigned short* wd2t = ws8 + (O_WD2T >> 1);
    unsigned short* wd3t = ws8 + (O_WD3T >> 1);
    unsigned short* wo2t = ws8 + (O_WO2T >> 1);
    unsigned short* wo3t = ws8 + (O_WO3T >> 1);
    if (i < 196608) {
        int o = i >> 9;
        float v = (o < 128) ? w1[i] : (o < 256) ? w21[i - 65536] : w31[i - 131072];
        wpb[i] = f2b(v);
    } else if (i < 262144) {
        unsigned j = i - 196608; w4b[j] = f2b(w4[j]);
    } else if (i < 524288) {
        unsigned j = i - 262144; wccb[j] = f2b(wcc[j]);
    } else if (i < 671744) {
        unsigned j = i - 524288; int t = j >> 14, o = (j >> 7) & 127, c = j & 127;
        wd2t[j] = f2b(wd2[((o * 128 + c) * 9) + t]);
    } else if (i < 1081344) {
        unsigned j = i - 671744; int t = j >> 14, o = (j >> 7) & 127, c = j & 127;
        wd3t[j] = f2b(wd3[((o * 128 + c) * 25) + t]);
    } else if (i < 1155072) {
        // layout (t, o, c): j = (t*64 + o)*128 + c
        unsigned j = i - 1081344; int t = j >> 13, o = (j >> 7) & 63, c = j & 127;
        wo2t[j] = (o < 18) ? f2b(wo2[((o * 128 + c) * 9) + t]) : 0;
    } else if (i < 1359872) {
        unsigned j = i - 1155072; int t = j >> 13, o = (j >> 7) & 63, c = j & 127;
        wo3t[j] = (o < 50) ? f2b(wo3[((o * 128 + c) * 25) + t]) : 0;
    }
}

// ---------------------------------------- x NCHW f32 -> NHWC bf16 transpose
__global__ __launch_bounds__(256) void k_xpose(const float* __restrict__ X,
                                               unsigned short* __restrict__ xbT) {
    __shared__ unsigned short t[32][33];
    const int p0 = blockIdx.x * 32, c0 = blockIdx.y * 32, b = blockIdx.z;
    const int tid = threadIdx.x;
    #pragma unroll
    for (int s = 0; s < 4; ++s) {
        int cl = s * 8 + (tid >> 5), pl = tid & 31;
        t[cl][pl] = f2b(X[((size_t)b * 512 + c0 + cl) * HW + p0 + pl]);
    }
    __syncthreads();
    #pragma unroll
    for (int s = 0; s < 4; ++s) {
        int pl = s * 8 + (tid >> 5), cl = tid & 31;
        xbT[((size_t)b * HW + p0 + pl) * 512 + c0 + cl] = t[cl][pl];
    }
}

// ----------------------------------------------- 3x3 s1 maxpool on NHWC bf16
__global__ __launch_bounds__(256) void k_pool(const unsigned short* __restrict__ xbT,
                                              unsigned short* __restrict__ pxb) {
    unsigned gid = blockIdx.x * 256 + threadIdx.x;   // 8*4096*64
    int b = gid >> 18;
    unsigned rem = gid & 262143;
    int pos = rem >> 6;
    int cg = (rem & 63) * 8;
    int h = pos >> 6, w = pos & 63;
    const unsigned short* img = xbT + (size_t)b * HW * 512;
    float m[8] = {-INFINITY, -INFINITY, -INFINITY, -INFINITY,
                  -INFINITY, -INFINITY, -INFINITY, -INFINITY};
    #pragma unroll
    for (int dy = -1; dy <= 1; ++dy) {
        int hh = h + dy;
        if (hh < 0 || hh >= 64) continue;
        #pragma unroll
        for (int dx = -1; dx <= 1; ++dx) {
            int ww = w + dx;
            if (ww < 0 || ww >= 64) continue;
            uint4 v = *(const uint4*)(img + ((size_t)(hh * 64 + ww)) * 512 + cg);
            unsigned uu[4] = {v.x, v.y, v.z, v.w};
            #pragma unroll
            for (int e = 0; e < 4; ++e) {
                m[2 * e]     = fmaxf(m[2 * e],     lou(uu[e]));
                m[2 * e + 1] = fmaxf(m[2 * e + 1], hiu(uu[e]));
            }
        }
    }
    uint4 o;
    o.x = pk2(m[0], m[1]); o.y = pk2(m[2], m[3]);
    o.z = pk2(m[4], m[5]); o.w = pk2(m[6], m[7]);
    *(uint4*)(pxb + ((size_t)b * HW + pos) * 512 + cg) = o;
}

// ----------------------------- bf16 MFMA GEMM: C[128 x 128pos] = A[128x512]B
#define SA(r,c) SM[(r)*40 + (c)]
#define SB(r,c) SM[5120 + (r)*40 + (c)]
#define SC(r,c) SM[(r)*136 + (c)]
__global__ __launch_bounds__(256) void k_gemm(
        const unsigned short* __restrict__ A, const float* __restrict__ bias,
        const unsigned short* __restrict__ Bm,
        unsigned short* __restrict__ dst, int dStride, int dOff) {
    __shared__ unsigned short SM[17408];
    const int tid = threadIdx.x;
    const int n0 = blockIdx.x * 128;
    const int b = blockIdx.z;
    const int wave = tid >> 6, lane = tid & 63, quad = lane >> 4, lr = lane & 15;
    const int m0w = (wave & 1) * 64, n0w = (wave >> 1) * 64;
    const int srow = tid >> 1, skh = (tid & 1) * 16;
    floatx4 acc[4][4] = {};

    for (int k0 = 0; k0 < 512; k0 += 32) {
        const unsigned short* ga = A + (size_t)srow * 512 + k0 + skh;
        uint4 a0 = *(const uint4*)(ga);
        uint4 a1 = *(const uint4*)(ga + 8);
        const unsigned short* gb = Bm + ((size_t)b * HW + n0 + srow) * 512 + k0 + skh;
        uint4 b0 = *(const uint4*)(gb);
        uint4 b1 = *(const uint4*)(gb + 8);
        __syncthreads();
        *(uint4*)&SA(srow, skh) = a0;
        *(uint4*)&SA(srow, skh + 8) = a1;
        *(uint4*)&SB(srow, skh) = b0;
        *(uint4*)&SB(srow, skh + 8) = b1;
        __syncthreads();
        short8 af[4], bf[4];
        #pragma unroll
        for (int i = 0; i < 4; ++i) af[i] = *(short8*)&SA(m0w + i * 16 + lr, quad * 8);
        #pragma unroll
        for (int j = 0; j < 4; ++j) bf[j] = *(short8*)&SB(n0w + j * 16 + lr, quad * 8);
        #pragma unroll
        for (int i = 0; i < 4; ++i)
            #pragma unroll
            for (int j = 0; j < 4; ++j)
                acc[i][j] = __builtin_amdgcn_mfma_f32_16x16x32_bf16(af[i], bf[j], acc[i][j], 0, 0, 0);
    }
    __syncthreads();
    #pragma unroll
    for (int i = 0; i < 4; ++i) {
        float4 bs = *(const float4*)&bias[m0w + i * 16 + quad * 4];
        #pragma unroll
        for (int j = 0; j < 4; ++j) {
            floatx4 v = acc[i][j];
            int pos = n0w + j * 16 + lr;
            int ch = m0w + i * 16 + quad * 4;
            uint2 st;
            st.x = pk2(v[0] + bs.x, v[1] + bs.y);
            st.y = pk2(v[2] + bs.z, v[3] + bs.w);
            *(uint2*)&SC(pos, ch) = st;
        }
    }
    __syncthreads();
    #pragma unroll
    for (int r = 0; r < 8; ++r) {
        int pos = (tid >> 4) + r * 16;
        *(uint4*)&dst[((size_t)b * HW + n0 + pos) * dStride + dOff + (tid & 15) * 8] =
            *(uint4*)&SC(pos, (tid & 15) * 8);
    }
}

// ---------------- offset convs v2: slab-staged, barrier-free tap loop
// block = 128 positions (2 h-rows) x 64 M (padded), 512 threads.
template<int KS, int OCH>
__global__ __launch_bounds__(512) void k_offconv2(
        const unsigned short* __restrict__ img,   // [B][4096][128] bf16
        const unsigned short* __restrict__ woT,   // [TT][64][128] bf16 (t,o,c)
        const float* __restrict__ bias, float* __restrict__ Out) {
    constexpr int PAD = KS / 2;
    constexpr int TT = KS * KS;
    constexpr int SR = 2 + 2 * PAD;
    constexpr int SC2 = 64 + 2 * PAD;
    constexpr int NE = SR * SC2;              // slab entries
    __shared__ unsigned short slab[NE * 36];  // [entry][36] (32 ch + pad)
    __shared__ float ctile[64 * 132];
    const int tid = threadIdx.x;
    const int p0 = blockIdx.x * 128, hrow0 = blockIdx.x * 2, b = blockIdx.z;
    const int wave = tid >> 6, lane = tid & 63, quad = lane >> 4, lr = lane & 15;
    const int wm = wave & 1, wn = wave >> 1;   // 2 x 4 wave grid: 32o x 32pos
    const unsigned short* ib = img + (size_t)b * HW * 128;
    floatx4 acc[2][2] = {};

    for (int c0 = 0; c0 < 128; c0 += 32) {
        __syncthreads();
        if (tid < NE) {
            int s = tid / SC2, cl = tid % SC2;
            int r = hrow0 - PAD + s, cc = cl - PAD;
            uint4 v0 = {}, v1 = {}, v2 = {}, v3 = {};
            if ((unsigned)r < 64u && (unsigned)cc < 64u) {
                const uint4* g = (const uint4*)(ib + ((size_t)(r * 64 + cc)) * 128 + c0);
                v0 = g[0]; v1 = g[1]; v2 = g[2]; v3 = g[3];
            }
            uint2* d2 = (uint2*)&slab[tid * 36];
            d2[0] = make_uint2(v0.x, v0.y); d2[1] = make_uint2(v0.z, v0.w);
            d2[2] = make_uint2(v1.x, v1.y); d2[3] = make_uint2(v1.z, v1.w);
            d2[4] = make_uint2(v2.x, v2.y); d2[5] = make_uint2(v2.z, v2.w);
            d2[6] = make_uint2(v3.x, v3.y); d2[7] = make_uint2(v3.z, v3.w);
        }
        __syncthreads();
        #pragma unroll
        for (int t = 0; t < TT; ++t) {
            const int ky = t / KS, kx = t % KS;
            short8 af[2], bf[2];
            #pragma unroll
            for (int i = 0; i < 2; ++i)
                af[i] = *(const short8*)&woT[((size_t)t * 64 + wm * 32 + i * 16 + lr) * 128
                                             + c0 + quad * 8];
            #pragma unroll
            for (int j = 0; j < 2; ++j) {
                int p = wn * 32 + j * 16 + lr;
                int e = ((p >> 6) + ky) * SC2 + (p & 63) + kx;
                union { uint2 u[2]; short8 s; } bb;
                const uint2* sp = (const uint2*)&slab[e * 36 + quad * 8];
                bb.u[0] = sp[0]; bb.u[1] = sp[1];
                bf[j] = bb.s;
            }
            #pragma unroll
            for (int i = 0; i < 2; ++i)
                #pragma unroll
                for (int j = 0; j < 2; ++j)
                    acc[i][j] = __builtin_amdgcn_mfma_f32_16x16x32_bf16(af[i], bf[j], acc[i][j], 0, 0, 0);
        }
    }
    __syncthreads();
    #pragma unroll
    for (int i = 0; i < 2; ++i)
        #pragma unroll
        for (int j = 0; j < 2; ++j) {
            floatx4 v = acc[i][j];
            int p = wn * 32 + j * 16 + lr;
            int o = wm * 32 + i * 16 + quad * 4;
            #pragma unroll
            for (int rg = 0; rg < 4; ++rg)
                ctile[(o + rg) * 132 + p] = v[rg];
        }
    __syncthreads();
    {
        int o = tid >> 3, seg = tid & 7;
        if (o < OCH) {
            float bs = bias[o];
            const float* src = &ctile[o * 132 + seg * 16];
            float* dst = &Out[((size_t)b * OCH + o) * HW + p0 + seg * 16];
            #pragma unroll
            for (int q = 0; q < 4; ++q) {
                float4 v = *(const float4*)(src + q * 4);
                v.x += bs; v.y += bs; v.z += bs; v.w += bs;
                *(float4*)(dst + q * 4) = v;
            }
        }
    }
}

// ---------------------- deformable conv v5: software-pipelined, 3 blocks/CU
// block = 256 threads (4 waves), tile = 128 o x 32 pos, grid = 128 x 8.
// Pipeline per tap: INTERP(t) | bar | LDS-write(t) | bar | issue loads(t+1),
// prefetch offsets(t+2) | MFMA(t).  In-flight loads cross no barrier.
template<int KS>
__global__ __launch_bounds__(256, 3) void k_deform5(
        const unsigned short* __restrict__ img,   // [B][4096][128] bf16
        const float* __restrict__ Off,            // [B][2TT][4096] f32
        const unsigned short* __restrict__ wdT,   // [TT][128][128] bf16 (t,o,c)
        const float* __restrict__ bias,
        unsigned short* __restrict__ catb, int dOff) {
    constexpr int PAD = KS / 2;
    constexpr int TT = KS * KS;
    __shared__ unsigned short sW[128][136];   // weights: [o][c], +8 pad
    __shared__ unsigned short sS[32][136];    // samples: [pos][c], +8 pad
    const int tid = threadIdx.x;
    const int b = blockIdx.z;
    const int p0 = blockIdx.x * 32;
    const int wave = tid >> 6, lane = tid & 63, quad = lane >> 4, lr = lane & 15;
    const int m0w = wave * 32;                // 4 waves cover 128 o-rows
    const int pos = tid >> 3;                 // 0..31
    const int cseg = (tid & 7) * 16;          // 16-ch segment
    const int pglob = p0 + pos;
    const int h = pglob >> 6, w = pglob & 63;
    const unsigned short* ib = img + (size_t)b * HW * 128;
    const float* offb = Off + (size_t)b * 2 * TT * HW;
    floatx4 acc[2][2] = {};

    uint4 wv[8];          // weight prefetch: 64 ushorts (row tid>>1, half tid&1)
    uint4 cn[8];          // 4 corners x 2 uint4 (16 ch)
    float w00, w01, w10, w11;

    auto ADDR = [&](int t, float dy, float dx) {
        float fy = (float)(h + t / KS - PAD) + dy;
        float fx = (float)(w + t % KS - PAD) + dx;
        float y0f = floorf(fy), x0f = floorf(fx);
        float wy = fy - y0f, wx = fx - x0f;
        int y0 = (int)y0f, x0 = (int)x0f;
        w00 = (1.f - wy) * (1.f - wx); w01 = (1.f - wy) * wx;
        w10 = wy * (1.f - wx);         w11 = wy * wx;
        bool yv0 = (unsigned)y0 < 64u, yv1 = (unsigned)(y0 + 1) < 64u;
        bool xv0 = (unsigned)x0 < 64u, xv1 = (unsigned)(x0 + 1) < 64u;
        long bidx = (long)(y0 * 64 + x0) * 128 + cseg;
        #pragma unroll
        for (int q = 0; q < 8; ++q) cn[q] = make_uint4(0u, 0u, 0u, 0u);
        if (yv0 && xv0) { const uint4* p = (const uint4*)(ib + bidx);
            cn[0] = p[0]; cn[1] = p[1]; }
        if (yv0 && xv1) { const uint4* p = (const uint4*)(ib + bidx + 128);
            cn[2] = p[0]; cn[3] = p[1]; }
        if (yv1 && xv0) { const uint4* p = (const uint4*)(ib + bidx + 8192);
            cn[4] = p[0]; cn[5] = p[1]; }
        if (yv1 && xv1) { const uint4* p = (const uint4*)(ib + bidx + 8320);
            cn[6] = p[0]; cn[7] = p[1]; }
        const uint4* wsrc = (const uint4*)(wdT + ((size_t)t * 128 + (tid >> 1)) * 128
                                           + (tid & 1) * 64);
        #pragma unroll
        for (int q = 0; q < 8; ++q) wv[q] = wsrc[q];
    };

    // prologue: ADDR(0) with offsets(0); prefetch offsets(1)
    {
        float coy = offb[pglob];
        float cox = offb[HW + pglob];
        ADDR(0, coy, cox);
    }
    float noy = 0.f, nox = 0.f;
    if (TT > 1) { noy = offb[2 * HW + pglob]; nox = offb[3 * HW + pglob]; }

    for (int t = 0; t < TT; ++t) {
        // INTERP(t): blend 4 corners -> 16 bf16 samples (2 uint4)
        uint4 s0, s1;
        {
            unsigned r[8];
            #pragma unroll
            for (int g = 0; g < 2; ++g) {
                unsigned au[4] = {cn[g].x,     cn[g].y,     cn[g].z,     cn[g].w};
                unsigned bu[4] = {cn[2 + g].x, cn[2 + g].y, cn[2 + g].z, cn[2 + g].w};
                unsigned cu[4] = {cn[4 + g].x, cn[4 + g].y, cn[4 + g].z, cn[4 + g].w};
                unsigned du[4] = {cn[6 + g].x, cn[6 + g].y, cn[6 + g].z, cn[6 + g].w};
                #pragma unroll
                for (int e = 0; e < 4; ++e) {
                    float lo = w00 * lou(au[e]) + w01 * lou(bu[e])
                             + w10 * lou(cu[e]) + w11 * lou(du[e]);
                    float hi = w00 * hiu(au[e]) + w01 * hiu(bu[e])
                             + w10 * hiu(cu[e]) + w11 * hiu(du[e]);
                    r[g * 4 + e] = pk2(lo, hi);
                }
            }
            s0 = make_uint4(r[0], r[1], r[2], r[3]);
            s1 = make_uint4(r[4], r[5], r[6], r[7]);
        }
        __syncthreads();
        // WRITE(t): stage weights + samples for this tap
        #pragma unroll
        for (int q = 0; q < 8; ++q)
            *(uint4*)&sW[tid >> 1][(tid & 1) * 64 + q * 8] = wv[q];
        *(uint4*)&sS[pos][cseg] = s0;
        *(uint4*)&sS[pos][cseg + 8] = s1;
        __syncthreads();
        // issue gather+weight loads for t+1 (in flight during MFMA below),
        // and prefetch offsets for t+2
        if (t + 1 < TT) {
            ADDR(t + 1, noy, nox);
            if (t + 2 < TT) {
                noy = offb[(size_t)(2 * t + 4) * HW + pglob];
                nox = offb[(size_t)(2 * t + 5) * HW + pglob];
            }
        }
        // MFMA(t)
        #pragma unroll
        for (int ks = 0; ks < 4; ++ks) {
            short8 af[2], bf[2];
            #pragma unroll
            for (int i = 0; i < 2; ++i)
                af[i] = *(short8*)&sW[m0w + i * 16 + lr][ks * 32 + quad * 8];
            #pragma unroll
            for (int j = 0; j < 2; ++j)
                bf[j] = *(short8*)&sS[j * 16 + lr][ks * 32 + quad * 8];
            #pragma unroll
            for (int i = 0; i < 2; ++i)
                #pragma unroll
                for (int j = 0; j < 2; ++j)
                    acc[i][j] = __builtin_amdgcn_mfma_f32_16x16x32_bf16(af[i], bf[j], acc[i][j], 0, 0, 0);
        }
    }
    // epilogue: bias + bf16 pack via sS, then coalesced store to catb
    __syncthreads();
    #pragma unroll
    for (int i = 0; i < 2; ++i) {
        float4 bs = *(const float4*)&bias[m0w + i * 16 + quad * 4];
        #pragma unroll
        for (int j = 0; j < 2; ++j) {
            floatx4 v = acc[i][j];
            int p = j * 16 + lr;
            int ch = m0w + i * 16 + quad * 4;
            uint2 st;
            st.x = pk2(v[0] + bs.x, v[1] + bs.y);
            st.y = pk2(v[2] + bs.z, v[3] + bs.w);
            *(uint2*)&sS[p][ch] = st;
        }
    }
    __syncthreads();
    #pragma unroll
    for (int r = 0; r < 2; ++r) {
        int idx = r * 256 + tid;
        int p = idx >> 4, sg = (idx & 15) * 8;
        *(uint4*)&catb[((size_t)b * HW + p0 + p) * 512 + dOff + sg] =
            *(uint4*)&sS[p][sg];
    }
}

// ------------------- final: sigmoid(Wcc @ (catb*xbT)) + x, fp32 NCHW output
__global__ __launch_bounds__(256) void k_gemm_final(
        const unsigned short* __restrict__ A, const float* __restrict__ bias,
        const unsigned short* __restrict__ catb, const unsigned short* __restrict__ xbT,
        const float* __restrict__ X, float* __restrict__ OutF) {
    __shared__ unsigned short sA[128][40];
    __shared__ unsigned short sB[128][40];
    const int tid = threadIdx.x;
    const int n0 = blockIdx.x * 128;
    const int o0 = blockIdx.y * 128;
    const int b = blockIdx.z;
    const int wave = tid >> 6, lane = tid & 63, quad = lane >> 4, lr = lane & 15;
    const int m0w = (wave & 1) * 64, n0w = (wave >> 1) * 64;
    const int srow = tid >> 1, skh = (tid & 1) * 16;
    floatx4 acc[4][4] = {};

    for (int k0 = 0; k0 < 512; k0 += 32) {
        const unsigned short* ga = A + (size_t)(o0 + srow) * 512 + k0 + skh;
        uint4 a0 = *(const uint4*)(ga);
        uint4 a1 = *(const uint4*)(ga + 8);
        size_t bi = ((size_t)b * HW + n0 + srow) * 512 + k0 + skh;
        uint4 c0 = *(const uint4*)(catb + bi);
        uint4 c1 = *(const uint4*)(catb + bi + 8);
        uint4 x0 = *(const uint4*)(xbT + bi);
        uint4 x1 = *(const uint4*)(xbT + bi + 8);
        unsigned cu[8] = {c0.x, c0.y, c0.z, c0.w, c1.x, c1.y, c1.z, c1.w};
        unsigned xu[8] = {x0.x, x0.y, x0.z, x0.w, x1.x, x1.y, x1.z, x1.w};
        unsigned mu[8];
        #pragma unroll
        for (int e = 0; e < 8; ++e)
            mu[e] = pk2(lou(cu[e]) * lou(xu[e]), hiu(cu[e]) * hiu(xu[e]));
        __syncthreads();
        *(uint4*)&sA[srow][skh] = a0;
        *(uint4*)&sA[srow][skh + 8] = a1;
        uint4 m0v; m0v.x = mu[0]; m0v.y = mu[1]; m0v.z = mu[2]; m0v.w = mu[3];
        uint4 m1v; m1v.x = mu[4]; m1v.y = mu[5]; m1v.z = mu[6]; m1v.w = mu[7];
        *(uint4*)&sB[srow][skh] = m0v;
        *(uint4*)&sB[srow][skh + 8] = m1v;
        __syncthreads();
        short8 af[4], bf[4];
        #pragma unroll
        for (int i = 0; i < 4; ++i) af[i] = *(short8*)&sA[m0w + i * 16 + lr][quad * 8];
        #pragma unroll
        for (int j = 0; j < 4; ++j) bf[j] = *(short8*)&sB[n0w + j * 16 + lr][quad * 8];
        #pragma unroll
        for (int i = 0; i < 4; ++i)
            #pragma unroll
            for (int j = 0; j < 4; ++j)
                acc[i][j] = __builtin_amdgcn_mfma_f32_16x16x32_bf16(af[i], bf[j], acc[i][j], 0, 0, 0);
    }
    #pragma unroll
    for (int i = 0; i < 4; ++i) {
        float4 bs = *(const float4*)&bias[o0 + m0w + i * 16 + quad * 4];
        float bsa[4] = {bs.x, bs.y, bs.z, bs.w};
        #pragma unroll
        for (int j = 0; j < 4; ++j) {
            floatx4 v = acc[i][j];
            int pos = n0 + n0w + j * 16 + lr;
            #pragma unroll
            for (int rg = 0; rg < 4; ++rg) {
                int o = o0 + m0w + i * 16 + quad * 4 + rg;
                float f = v[rg] + bsa[rg];
                float sg = 1.f / (1.f + __expf(-f));
                size_t idx = ((size_t)b * 512 + o) * HW + pos;
                OutF[idx] = X[idx] + sg;
            }
        }
    }
}

// ------------------------------------------------------------------- launcher
extern "C" void kernel_launch(void* const* d_in, const int* in_sizes, int n_in,
                              void* d_out, int out_size, void* d_ws, size_t ws_size,
                              hipStream_t stream) {
    const float* x      = (const float*)d_in[0];
    const float* w_b1   = (const float*)d_in[1];
    const float* b_b1   = (const float*)d_in[2];
    const float* w_b21  = (const float*)d_in[3];
    const float* b_b21  = (const float*)d_in[4];
    const float* w_off2 = (const float*)d_in[5];
    const float* b_off2 = (const float*)d_in[6];
    const float* w_ddc2 = (const float*)d_in[7];
    const float* b_ddc2 = (const float*)d_in[8];
    const float* w_b31  = (const float*)d_in[9];
    const float* b_b31  = (const float*)d_in[10];
    const float* w_off3 = (const float*)d_in[11];
    const float* b_off3 = (const float*)d_in[12];
    const float* w_ddc3 = (const float*)d_in[13];
    const float* b_ddc3 = (const float*)d_in[14];
    const float* w_b4   = (const float*)d_in[15];
    const float* b_b4   = (const float*)d_in[16];
    const float* w_cc   = (const float*)d_in[17];
    const float* b_cc   = (const float*)d_in[18];

    char* wsb = (char*)d_ws;
    unsigned short* ws8  = (unsigned short*)d_ws;
    unsigned short* xbT  = (unsigned short*)(wsb + O_XBT);
    unsigned short* pxb  = (unsigned short*)(wsb + O_PXB);
    unsigned short* catb = (unsigned short*)(wsb + O_CATB);
    unsigned short* wpb  = (unsigned short*)(wsb + O_WPB);
    unsigned short* w4b  = (unsigned short*)(wsb + O_W4B);
    unsigned short* wccb = (unsigned short*)(wsb + O_WCCB);
    unsigned short* wd2t = (unsigned short*)(wsb + O_WD2T);
    unsigned short* wd3t = (unsigned short*)(wsb + O_WD3T);
    unsigned short* wo2t = (unsigned short*)(wsb + O_WO2T);
    unsigned short* wo3t = (unsigned short*)(wsb + O_WO3T);
    unsigned short* t2b  = (unsigned short*)(wsb + O_T2B);
    unsigned short* t3b  = (unsigned short*)(wsb + O_T3B);
    float* off2 = (float*)(wsb + O_OFF2);
    float* off3 = (float*)(wsb + O_OFF3);
    float* out  = (float*)d_out;

    k_prepw<<<dim3(5312), dim3(256), 0, stream>>>(
        w_b1, w_b21, w_b31, w_b4, w_cc, w_ddc2, w_ddc3, w_off2, w_off3, ws8);
    k_xpose<<<dim3(128, 16, 8), dim3(256), 0, stream>>>(x, xbT);
    k_pool<<<dim3(8192), dim3(256), 0, stream>>>(xbT, pxb);
    // b4 first (frees pxb region for t2b/t3b/offsets)
    k_gemm<<<dim3(32, 1, 8), dim3(256), 0, stream>>>(w4b, b_b4, pxb, catb, 512, 384);
    k_gemm<<<dim3(32, 1, 8), dim3(256), 0, stream>>>(wpb, b_b1, xbT, catb, 512, 0);
    k_gemm<<<dim3(32, 1, 8), dim3(256), 0, stream>>>(wpb + 128 * 512, b_b21, xbT, t2b, 128, 0);
    k_gemm<<<dim3(32, 1, 8), dim3(256), 0, stream>>>(wpb + 256 * 512, b_b31, xbT, t3b, 128, 0);
    k_offconv2<3, 18><<<dim3(32, 1, 8), dim3(512), 0, stream>>>(t2b, wo2t, b_off2, off2);
    k_offconv2<5, 50><<<dim3(32, 1, 8), dim3(512), 0, stream>>>(t3b, wo3t, b_off3, off3);
    k_deform5<3><<<dim3(128, 1, 8), dim3(256), 0, stream>>>(t2b, off2, wd2t, b_ddc2, catb, 128);
    k_deform5<5><<<dim3(128, 1, 8), dim3(256), 0, stream>>>(t3b, off3, wd3t, b_ddc3, catb, 256);
    k_gemm_final<<<dim3(32, 4, 8), dim3(256), 0, stream>>>(wccb, b_cc, catb, xbT, x, out);
}

// Round 2
// 603.369 us; speedup vs baseline: 1.3265x; 1.3265x over previous
//
#include <hip/hip_runtime.h>
#include <math.h>

#define HW 4096
typedef short short8 __attribute__((ext_vector_type(8)));
typedef float floatx4 __attribute__((ext_vector_type(4)));

// ---- ws layout (bytes) ----
#define O_XBT   0ull            // [8][4096][512] bf16 x NHWC
#define O_PXB   33554432ull     // [8][4096][512] bf16 pooled x NHWC (reused later)
#define O_CATB  67108864ull     // [8][4096][512] bf16 cat branches NHWC
#define O_WPB   100663296ull    // [384][512] bf16
#define O_W4B   101056512ull    // [128][512] bf16
#define O_WCCB  101187584ull    // [512][512] bf16
#define O_WD2T  101711872ull    // [9][128][128] bf16 (t,o,c)
#define O_WD3T  102006784ull    // [25][128][128] bf16 (t,o,c)
#define O_WO2T  102825984ull    // [9][64][128] bf16 (t,o,c)
#define O_WO3T  102973440ull    // [25][64][128] bf16 (t,o,c)
// reuse of PXB region after b4 GEMM:
#define O_T2B   33554432ull     // [8][4096][128] bf16 b2i NHWC
#define O_T3B   41943040ull     // [8][4096][128] bf16 b3i NHWC
#define O_OFF2  50331648ull     // [8][18][4096] f32
#define O_OFF3  52690944ull     // [8][50][4096] f32

__device__ __forceinline__ unsigned short f2b(float f) {
    union { float f; unsigned u; } v; v.f = f;
    unsigned r = v.u + 0x7FFFu + ((v.u >> 16) & 1u);
    return (unsigned short)(r >> 16);
}
__device__ __forceinline__ float lou(unsigned u) {
    union { unsigned u; float f; } v; v.u = u << 16; return v.f;
}
__device__ __forceinline__ float hiu(unsigned u) {
    union { unsigned u; float f; } v; v.u = u & 0xFFFF0000u; return v.f;
}
__device__ __forceinline__ unsigned pk2(float lo, float hi) {
    return (unsigned)f2b(lo) | ((unsigned)f2b(hi) << 16);
}

// ------------------------------------------------------------- weight prep
__global__ __launch_bounds__(256) void k_prepw(
        const float* __restrict__ w1, const float* __restrict__ w21,
        const float* __restrict__ w31, const float* __restrict__ w4,
        const float* __restrict__ wcc, const float* __restrict__ wd2,
        const float* __restrict__ wd3, const float* __restrict__ wo2,
        const float* __restrict__ wo3, unsigned short* __restrict__ ws8) {
    unsigned i = blockIdx.x * 256 + threadIdx.x;
    unsigned short* wpb  = ws8 + (O_WPB  >> 1);
    unsigned short* w4b  = ws8 + (O_W4B  >> 1);
    unsigned short* wccb = ws8 + (O_WCCB >> 1);
    unsigned short* wd2t = ws8 + (O_WD2T >> 1);
    unsigned short* wd3t = ws8 + (O_WD3T >> 1);
    unsigned short* wo2t = ws8 + (O_WO2T >> 1);
    unsigned short* wo3t = ws8 + (O_WO3T >> 1);
    if (i < 196608) {
        int o = i >> 9;
        float v = (o < 128) ? w1[i] : (o < 256) ? w21[i - 65536] : w31[i - 131072];
        wpb[i] = f2b(v);
    } else if (i < 262144) {
        unsigned j = i - 196608; w4b[j] = f2b(w4[j]);
    } else if (i < 524288) {
        unsigned j = i - 262144; wccb[j] = f2b(wcc[j]);
    } else if (i < 671744) {
        unsigned j = i - 524288; int t = j >> 14, o = (j >> 7) & 127, c = j & 127;
        wd2t[j] = f2b(wd2[((o * 128 + c) * 9) + t]);
    } else if (i < 1081344) {
        unsigned j = i - 671744; int t = j >> 14, o = (j >> 7) & 127, c = j & 127;
        wd3t[j] = f2b(wd3[((o * 128 + c) * 25) + t]);
    } else if (i < 1155072) {
        // layout (t, o, c): j = (t*64 + o)*128 + c
        unsigned j = i - 1081344; int t = j >> 13, o = (j >> 7) & 63, c = j & 127;
        wo2t[j] = (o < 18) ? f2b(wo2[((o * 128 + c) * 9) + t]) : 0;
    } else if (i < 1359872) {
        unsigned j = i - 1155072; int t = j >> 13, o = (j >> 7) & 63, c = j & 127;
        wo3t[j] = (o < 50) ? f2b(wo3[((o * 128 + c) * 25) + t]) : 0;
    }
}

// ---------------------------------------- x NCHW f32 -> NHWC bf16 transpose
__global__ __launch_bounds__(256) void k_xpose(const float* __restrict__ X,
                                               unsigned short* __restrict__ xbT) {
    __shared__ unsigned short t[32][33];
    const int p0 = blockIdx.x * 32, c0 = blockIdx.y * 32, b = blockIdx.z;
    const int tid = threadIdx.x;
    #pragma unroll
    for (int s = 0; s < 4; ++s) {
        int cl = s * 8 + (tid >> 5), pl = tid & 31;
        t[cl][pl] = f2b(X[((size_t)b * 512 + c0 + cl) * HW + p0 + pl]);
    }
    __syncthreads();
    #pragma unroll
    for (int s = 0; s < 4; ++s) {
        int pl = s * 8 + (tid >> 5), cl = tid & 31;
        xbT[((size_t)b * HW + p0 + pl) * 512 + c0 + cl] = t[cl][pl];
    }
}

// ----------------------------------------------- 3x3 s1 maxpool on NHWC bf16
__global__ __launch_bounds__(256) void k_pool(const unsigned short* __restrict__ xbT,
                                              unsigned short* __restrict__ pxb) {
    unsigned gid = blockIdx.x * 256 + threadIdx.x;   // 8*4096*64
    int b = gid >> 18;
    unsigned rem = gid & 262143;
    int pos = rem >> 6;
    int cg = (rem & 63) * 8;
    int h = pos >> 6, w = pos & 63;
    const unsigned short* img = xbT + (size_t)b * HW * 512;
    float m[8] = {-INFINITY, -INFINITY, -INFINITY, -INFINITY,
                  -INFINITY, -INFINITY, -INFINITY, -INFINITY};
    #pragma unroll
    for (int dy = -1; dy <= 1; ++dy) {
        int hh = h + dy;
        if (hh < 0 || hh >= 64) continue;
        #pragma unroll
        for (int dx = -1; dx <= 1; ++dx) {
            int ww = w + dx;
            if (ww < 0 || ww >= 64) continue;
            uint4 v = *(const uint4*)(img + ((size_t)(hh * 64 + ww)) * 512 + cg);
            unsigned uu[4] = {v.x, v.y, v.z, v.w};
            #pragma unroll
            for (int e = 0; e < 4; ++e) {
                m[2 * e]     = fmaxf(m[2 * e],     lou(uu[e]));
                m[2 * e + 1] = fmaxf(m[2 * e + 1], hiu(uu[e]));
            }
        }
    }
    uint4 o;
    o.x = pk2(m[0], m[1]); o.y = pk2(m[2], m[3]);
    o.z = pk2(m[4], m[5]); o.w = pk2(m[6], m[7]);
    *(uint4*)(pxb + ((size_t)b * HW + pos) * 512 + cg) = o;
}

// ----------------------------- bf16 MFMA GEMM: C[128 x 128pos] = A[128x512]B
#define SA(r,c) SM[(r)*40 + (c)]
#define SB(r,c) SM[5120 + (r)*40 + (c)]
#define SC(r,c) SM[(r)*136 + (c)]
__global__ __launch_bounds__(256) void k_gemm(
        const unsigned short* __restrict__ A, const float* __restrict__ bias,
        const unsigned short* __restrict__ Bm,
        unsigned short* __restrict__ dst, int dStride, int dOff) {
    __shared__ unsigned short SM[17408];
    const int tid = threadIdx.x;
    const int n0 = blockIdx.x * 128;
    const int b = blockIdx.z;
    const int wave = tid >> 6, lane = tid & 63, quad = lane >> 4, lr = lane & 15;
    const int m0w = (wave & 1) * 64, n0w = (wave >> 1) * 64;
    const int srow = tid >> 1, skh = (tid & 1) * 16;
    floatx4 acc[4][4] = {};

    for (int k0 = 0; k0 < 512; k0 += 32) {
        const unsigned short* ga = A + (size_t)srow * 512 + k0 + skh;
        uint4 a0 = *(const uint4*)(ga);
        uint4 a1 = *(const uint4*)(ga + 8);
        const unsigned short* gb = Bm + ((size_t)b * HW + n0 + srow) * 512 + k0 + skh;
        uint4 b0 = *(const uint4*)(gb);
        uint4 b1 = *(const uint4*)(gb + 8);
        __syncthreads();
        *(uint4*)&SA(srow, skh) = a0;
        *(uint4*)&SA(srow, skh + 8) = a1;
        *(uint4*)&SB(srow, skh) = b0;
        *(uint4*)&SB(srow, skh + 8) = b1;
        __syncthreads();
        short8 af[4], bf[4];
        #pragma unroll
        for (int i = 0; i < 4; ++i) af[i] = *(short8*)&SA(m0w + i * 16 + lr, quad * 8);
        #pragma unroll
        for (int j = 0; j < 4; ++j) bf[j] = *(short8*)&SB(n0w + j * 16 + lr, quad * 8);
        #pragma unroll
        for (int i = 0; i < 4; ++i)
            #pragma unroll
            for (int j = 0; j < 4; ++j)
                acc[i][j] = __builtin_amdgcn_mfma_f32_16x16x32_bf16(af[i], bf[j], acc[i][j], 0, 0, 0);
    }
    __syncthreads();
    #pragma unroll
    for (int i = 0; i < 4; ++i) {
        float4 bs = *(const float4*)&bias[m0w + i * 16 + quad * 4];
        #pragma unroll
        for (int j = 0; j < 4; ++j) {
            floatx4 v = acc[i][j];
            int pos = n0w + j * 16 + lr;
            int ch = m0w + i * 16 + quad * 4;
            uint2 st;
            st.x = pk2(v[0] + bs.x, v[1] + bs.y);
            st.y = pk2(v[2] + bs.z, v[3] + bs.w);
            *(uint2*)&SC(pos, ch) = st;
        }
    }
    __syncthreads();
    #pragma unroll
    for (int r = 0; r < 8; ++r) {
        int pos = (tid >> 4) + r * 16;
        *(uint4*)&dst[((size_t)b * HW + n0 + pos) * dStride + dOff + (tid & 15) * 8] =
            *(uint4*)&SC(pos, (tid & 15) * 8);
    }
}

// ---------------- offset convs v2: slab-staged, barrier-free tap loop
// block = 128 positions (2 h-rows) x 64 M (padded), 512 threads.
template<int KS, int OCH>
__global__ __launch_bounds__(512) void k_offconv2(
        const unsigned short* __restrict__ img,   // [B][4096][128] bf16
        const unsigned short* __restrict__ woT,   // [TT][64][128] bf16 (t,o,c)
        const float* __restrict__ bias, float* __restrict__ Out) {
    constexpr int PAD = KS / 2;
    constexpr int TT = KS * KS;
    constexpr int SR = 2 + 2 * PAD;
    constexpr int SC2 = 64 + 2 * PAD;
    constexpr int NE = SR * SC2;              // slab entries
    __shared__ unsigned short slab[NE * 36];  // [entry][36] (32 ch + pad)
    __shared__ float ctile[64 * 132];
    const int tid = threadIdx.x;
    const int p0 = blockIdx.x * 128, hrow0 = blockIdx.x * 2, b = blockIdx.z;
    const int wave = tid >> 6, lane = tid & 63, quad = lane >> 4, lr = lane & 15;
    const int wm = wave & 1, wn = wave >> 1;   // 2 x 4 wave grid: 32o x 32pos
    const unsigned short* ib = img + (size_t)b * HW * 128;
    floatx4 acc[2][2] = {};

    for (int c0 = 0; c0 < 128; c0 += 32) {
        __syncthreads();
        if (tid < NE) {
            int s = tid / SC2, cl = tid % SC2;
            int r = hrow0 - PAD + s, cc = cl - PAD;
            uint4 v0 = {}, v1 = {}, v2 = {}, v3 = {};
            if ((unsigned)r < 64u && (unsigned)cc < 64u) {
                const uint4* g = (const uint4*)(ib + ((size_t)(r * 64 + cc)) * 128 + c0);
                v0 = g[0]; v1 = g[1]; v2 = g[2]; v3 = g[3];
            }
            uint2* d2 = (uint2*)&slab[tid * 36];
            d2[0] = make_uint2(v0.x, v0.y); d2[1] = make_uint2(v0.z, v0.w);
            d2[2] = make_uint2(v1.x, v1.y); d2[3] = make_uint2(v1.z, v1.w);
            d2[4] = make_uint2(v2.x, v2.y); d2[5] = make_uint2(v2.z, v2.w);
            d2[6] = make_uint2(v3.x, v3.y); d2[7] = make_uint2(v3.z, v3.w);
        }
        __syncthreads();
        #pragma unroll
        for (int t = 0; t < TT; ++t) {
            const int ky = t / KS, kx = t % KS;
            short8 af[2], bf[2];
            #pragma unroll
            for (int i = 0; i < 2; ++i)
                af[i] = *(const short8*)&woT[((size_t)t * 64 + wm * 32 + i * 16 + lr) * 128
                                             + c0 + quad * 8];
            #pragma unroll
            for (int j = 0; j < 2; ++j) {
                int p = wn * 32 + j * 16 + lr;
                int e = ((p >> 6) + ky) * SC2 + (p & 63) + kx;
                union { uint2 u[2]; short8 s; } bb;
                const uint2* sp = (const uint2*)&slab[e * 36 + quad * 8];
                bb.u[0] = sp[0]; bb.u[1] = sp[1];
                bf[j] = bb.s;
            }
            #pragma unroll
            for (int i = 0; i < 2; ++i)
                #pragma unroll
                for (int j = 0; j < 2; ++j)
                    acc[i][j] = __builtin_amdgcn_mfma_f32_16x16x32_bf16(af[i], bf[j], acc[i][j], 0, 0, 0);
        }
    }
    __syncthreads();
    #pragma unroll
    for (int i = 0; i < 2; ++i)
        #pragma unroll
        for (int j = 0; j < 2; ++j) {
            floatx4 v = acc[i][j];
            int p = wn * 32 + j * 16 + lr;
            int o = wm * 32 + i * 16 + quad * 4;
            #pragma unroll
            for (int rg = 0; rg < 4; ++rg)
                ctile[(o + rg) * 132 + p] = v[rg];
        }
    __syncthreads();
    {
        int o = tid >> 3, seg = tid & 7;
        if (o < OCH) {
            float bs = bias[o];
            const float* src = &ctile[o * 132 + seg * 16];
            float* dst = &Out[((size_t)b * OCH + o) * HW + p0 + seg * 16];
            #pragma unroll
            for (int q = 0; q < 4; ++q) {
                float4 v = *(const float4*)(src + q * 4);
                v.x += bs; v.y += bs; v.z += bs; v.w += bs;
                *(float4*)(dst + q * 4) = v;
            }
        }
    }
}

// ---------------------- deformable conv v6: v4 structure, half-size tile
// block = 512 threads (8 waves), tile = 128 o x 64 pos, grid = 64 x 8
// -> 2 blocks/CU (LDS 52.2 KB), inter-block overlap hides phase bubbles.
// Per-thread corner footprint halved (16 ch) to stay spill-free.
template<int KS>
__global__ __launch_bounds__(512) void k_deform6(
        const unsigned short* __restrict__ img,   // [B][4096][128] bf16
        const float* __restrict__ Off,            // [B][2TT][4096] f32
        const unsigned short* __restrict__ wdT,   // [TT][128][128] bf16 (t,o,c)
        const float* __restrict__ bias,
        unsigned short* __restrict__ catb, int dOff) {
    constexpr int PAD = KS / 2;
    constexpr int TT = KS * KS;
    __shared__ unsigned short sW[128][136];   // weights [o][c], +8 pad
    __shared__ unsigned short sS[64][136];    // samples [pos][c], +8 pad
    const int tid = threadIdx.x;
    const int b = blockIdx.z;
    const int p0 = blockIdx.x * 64;           // one h-row per block
    const int wave = tid >> 6, lane = tid & 63, quad = lane >> 4, lr = lane & 15;
    const int m0w = (wave & 3) * 32;          // 4 m-waves x 32 o
    const int n0w = (wave >> 2) * 32;         // 2 n-waves x 32 pos
    const int pos = tid >> 3;                 // 0..63
    const int cseg = (tid & 7) * 16;          // 16-ch segment
    const int pglob = p0 + pos;
    const int h = blockIdx.x, w = pos;
    const unsigned short* ib = img + (size_t)b * HW * 128;
    const float* offb = Off + (size_t)b * 2 * TT * HW;
    floatx4 acc[2][2] = {};

    for (int t = 0; t < TT; ++t) {
        float dy = offb[(size_t)(2 * t) * HW + pglob];
        float dx = offb[(size_t)(2 * t + 1) * HW + pglob];
        float fy = (float)(h + t / KS - PAD) + dy;
        float fx = (float)(w + t % KS - PAD) + dx;
        float y0f = floorf(fy), x0f = floorf(fx);
        float wy = fy - y0f, wx = fx - x0f;
        int y0 = (int)y0f, x0 = (int)x0f;
        float w00 = (1.f - wy) * (1.f - wx), w01 = (1.f - wy) * wx;
        float w10 = wy * (1.f - wx), w11 = wy * wx;
        const uint4* wsrc = (const uint4*)(wdT + ((size_t)t * 128 + (tid >> 2)) * 128
                                           + (tid & 3) * 32);
        uint4 wv[4] = {wsrc[0], wsrc[1], wsrc[2], wsrc[3]};
        bool yv0 = (unsigned)y0 < 64u, yv1 = (unsigned)(y0 + 1) < 64u;
        bool xv0 = (unsigned)x0 < 64u, xv1 = (unsigned)(x0 + 1) < 64u;
        uint4 cA[2] = {}, cB[2] = {}, cC[2] = {}, cD[2] = {};
        long bidx = (long)(y0 * 64 + x0) * 128 + cseg;
        if (yv0 && xv0) { const uint4* p = (const uint4*)(ib + bidx);
            cA[0] = p[0]; cA[1] = p[1]; }
        if (yv0 && xv1) { const uint4* p = (const uint4*)(ib + bidx + 128);
            cB[0] = p[0]; cB[1] = p[1]; }
        if (yv1 && xv0) { const uint4* p = (const uint4*)(ib + bidx + 8192);
            cC[0] = p[0]; cC[1] = p[1]; }
        if (yv1 && xv1) { const uint4* p = (const uint4*)(ib + bidx + 8320);
            cD[0] = p[0]; cD[1] = p[1]; }
        uint4 outv[2];
        #pragma unroll
        for (int j = 0; j < 2; ++j) {
            unsigned a[4] = {cA[j].x, cA[j].y, cA[j].z, cA[j].w};
            unsigned bb[4] = {cB[j].x, cB[j].y, cB[j].z, cB[j].w};
            unsigned c[4] = {cC[j].x, cC[j].y, cC[j].z, cC[j].w};
            unsigned d[4] = {cD[j].x, cD[j].y, cD[j].z, cD[j].w};
            unsigned r[4];
            #pragma unroll
            for (int e = 0; e < 4; ++e) {
                float lo = w00 * lou(a[e]) + w01 * lou(bb[e]) + w10 * lou(c[e]) + w11 * lou(d[e]);
                float hi = w00 * hiu(a[e]) + w01 * hiu(bb[e]) + w10 * hiu(c[e]) + w11 * hiu(d[e]);
                r[e] = pk2(lo, hi);
            }
            outv[j].x = r[0]; outv[j].y = r[1]; outv[j].z = r[2]; outv[j].w = r[3];
        }
        __syncthreads();
        #pragma unroll
        for (int q = 0; q < 4; ++q)
            *(uint4*)&sW[tid >> 2][(tid & 3) * 32 + q * 8] = wv[q];
        *(uint4*)&sS[pos][cseg] = outv[0];
        *(uint4*)&sS[pos][cseg + 8] = outv[1];
        __syncthreads();
        #pragma unroll
        for (int ks = 0; ks < 4; ++ks) {
            short8 af[2], bf[2];
            #pragma unroll
            for (int i = 0; i < 2; ++i)
                af[i] = *(short8*)&sW[m0w + i * 16 + lr][ks * 32 + quad * 8];
            #pragma unroll
            for (int j = 0; j < 2; ++j)
                bf[j] = *(short8*)&sS[n0w + j * 16 + lr][ks * 32 + quad * 8];
            #pragma unroll
            for (int i = 0; i < 2; ++i)
                #pragma unroll
                for (int j = 0; j < 2; ++j)
                    acc[i][j] = __builtin_amdgcn_mfma_f32_16x16x32_bf16(af[i], bf[j], acc[i][j], 0, 0, 0);
        }
    }
    // epilogue: bias + bf16 pack via sW rows 0..63, coalesced store to catb
    __syncthreads();
    #pragma unroll
    for (int i = 0; i < 2; ++i) {
        float4 bs = *(const float4*)&bias[m0w + i * 16 + quad * 4];
        #pragma unroll
        for (int j = 0; j < 2; ++j) {
            floatx4 v = acc[i][j];
            int p = n0w + j * 16 + lr;
            int ch = m0w + i * 16 + quad * 4;
            uint2 st;
            st.x = pk2(v[0] + bs.x, v[1] + bs.y);
            st.y = pk2(v[2] + bs.z, v[3] + bs.w);
            *(uint2*)&sW[p][ch] = st;
        }
    }
    __syncthreads();
    #pragma unroll
    for (int r = 0; r < 2; ++r) {
        int idx = r * 512 + tid;
        int p = idx >> 4, sg = (idx & 15) * 8;
        *(uint4*)&catb[((size_t)b * HW + p0 + p) * 512 + dOff + sg] =
            *(uint4*)&sW[p][sg];
    }
}

// ------------------- final: sigmoid(Wcc @ (catb*xbT)) + x, fp32 NCHW output
__global__ __launch_bounds__(256) void k_gemm_final(
        const unsigned short* __restrict__ A, const float* __restrict__ bias,
        const unsigned short* __restrict__ catb, const unsigned short* __restrict__ xbT,
        const float* __restrict__ X, float* __restrict__ OutF) {
    __shared__ unsigned short sA[128][40];
    __shared__ unsigned short sB[128][40];
    const int tid = threadIdx.x;
    const int n0 = blockIdx.x * 128;
    const int o0 = blockIdx.y * 128;
    const int b = blockIdx.z;
    const int wave = tid >> 6, lane = tid & 63, quad = lane >> 4, lr = lane & 15;
    const int m0w = (wave & 1) * 64, n0w = (wave >> 1) * 64;
    const int srow = tid >> 1, skh = (tid & 1) * 16;
    floatx4 acc[4][4] = {};

    for (int k0 = 0; k0 < 512; k0 += 32) {
        const unsigned short* ga = A + (size_t)(o0 + srow) * 512 + k0 + skh;
        uint4 a0 = *(const uint4*)(ga);
        uint4 a1 = *(const uint4*)(ga + 8);
        size_t bi = ((size_t)b * HW + n0 + srow) * 512 + k0 + skh;
        uint4 c0 = *(const uint4*)(catb + bi);
        uint4 c1 = *(const uint4*)(catb + bi + 8);
        uint4 x0 = *(const uint4*)(xbT + bi);
        uint4 x1 = *(const uint4*)(xbT + bi + 8);
        unsigned cu[8] = {c0.x, c0.y, c0.z, c0.w, c1.x, c1.y, c1.z, c1.w};
        unsigned xu[8] = {x0.x, x0.y, x0.z, x0.w, x1.x, x1.y, x1.z, x1.w};
        unsigned mu[8];
        #pragma unroll
        for (int e = 0; e < 8; ++e)
            mu[e] = pk2(lou(cu[e]) * lou(xu[e]), hiu(cu[e]) * hiu(xu[e]));
        __syncthreads();
        *(uint4*)&sA[srow][skh] = a0;
        *(uint4*)&sA[srow][skh + 8] = a1;
        uint4 m0v; m0v.x = mu[0]; m0v.y = mu[1]; m0v.z = mu[2]; m0v.w = mu[3];
        uint4 m1v; m1v.x = mu[4]; m1v.y = mu[5]; m1v.z = mu[6]; m1v.w = mu[7];
        *(uint4*)&sB[srow][skh] = m0v;
        *(uint4*)&sB[srow][skh + 8] = m1v;
        __syncthreads();
        short8 af[4], bf[4];
        #pragma unroll
        for (int i = 0; i < 4; ++i) af[i] = *(short8*)&sA[m0w + i * 16 + lr][quad * 8];
        #pragma unroll
        for (int j = 0; j < 4; ++j) bf[j] = *(short8*)&sB[n0w + j * 16 + lr][quad * 8];
        #pragma unroll
        for (int i = 0; i < 4; ++i)
            #pragma unroll
            for (int j = 0; j < 4; ++j)
                acc[i][j] = __builtin_amdgcn_mfma_f32_16x16x32_bf16(af[i], bf[j], acc[i][j], 0, 0, 0);
    }
    #pragma unroll
    for (int i = 0; i < 4; ++i) {
        float4 bs = *(const float4*)&bias[o0 + m0w + i * 16 + quad * 4];
        float bsa[4] = {bs.x, bs.y, bs.z, bs.w};
        #pragma unroll
        for (int j = 0; j < 4; ++j) {
            floatx4 v = acc[i][j];
            int pos = n0 + n0w + j * 16 + lr;
            #pragma unroll
            for (int rg = 0; rg < 4; ++rg) {
                int o = o0 + m0w + i * 16 + quad * 4 + rg;
                float f = v[rg] + bsa[rg];
                float sg = 1.f / (1.f + __expf(-f));
                size_t idx = ((size_t)b * 512 + o) * HW + pos;
                OutF[idx] = X[idx] + sg;
            }
        }
    }
}

// ------------------------------------------------------------------- launcher
extern "C" void kernel_launch(void* const* d_in, const int* in_sizes, int n_in,
                              void* d_out, int out_size, void* d_ws, size_t ws_size,
                              hipStream_t stream) {
    const float* x      = (const float*)d_in[0];
    const float* w_b1   = (const float*)d_in[1];
    const float* b_b1   = (const float*)d_in[2];
    const float* w_b21  = (const float*)d_in[3];
    const float* b_b21  = (const float*)d_in[4];
    const float* w_off2 = (const float*)d_in[5];
    const float* b_off2 = (const float*)d_in[6];
    const float* w_ddc2 = (const float*)d_in[7];
    const float* b_ddc2 = (const float*)d_in[8];
    const float* w_b31  = (const float*)d_in[9];
    const float* b_b31  = (const float*)d_in[10];
    const float* w_off3 = (const float*)d_in[11];
    const float* b_off3 = (const float*)d_in[12];
    const float* w_ddc3 = (const float*)d_in[13];
    const float* b_ddc3 = (const float*)d_in[14];
    const float* w_b4   = (const float*)d_in[15];
    const float* b_b4   = (const float*)d_in[16];
    const float* w_cc   = (const float*)d_in[17];
    const float* b_cc   = (const float*)d_in[18];

    char* wsb = (char*)d_ws;
    unsigned short* ws8  = (unsigned short*)d_ws;
    unsigned short* xbT  = (unsigned short*)(wsb + O_XBT);
    unsigned short* pxb  = (unsigned short*)(wsb + O_PXB);
    unsigned short* catb = (unsigned short*)(wsb + O_CATB);
    unsigned short* wpb  = (unsigned short*)(wsb + O_WPB);
    unsigned short* w4b  = (unsigned short*)(wsb + O_W4B);
    unsigned short* wccb = (unsigned short*)(wsb + O_WCCB);
    unsigned short* wd2t = (unsigned short*)(wsb + O_WD2T);
    unsigned short* wd3t = (unsigned short*)(wsb + O_WD3T);
    unsigned short* wo2t = (unsigned short*)(wsb + O_WO2T);
    unsigned short* wo3t = (unsigned short*)(wsb + O_WO3T);
    unsigned short* t2b  = (unsigned short*)(wsb + O_T2B);
    unsigned short* t3b  = (unsigned short*)(wsb + O_T3B);
    float* off2 = (float*)(wsb + O_OFF2);
    float* off3 = (float*)(wsb + O_OFF3);
    float* out  = (float*)d_out;

    k_prepw<<<dim3(5312), dim3(256), 0, stream>>>(
        w_b1, w_b21, w_b31, w_b4, w_cc, w_ddc2, w_ddc3, w_off2, w_off3, ws8);
    k_xpose<<<dim3(128, 16, 8), dim3(256), 0, stream>>>(x, xbT);
    k_pool<<<dim3(8192), dim3(256), 0, stream>>>(xbT, pxb);
    // b4 first (frees pxb region for t2b/t3b/offsets)
    k_gemm<<<dim3(32, 1, 8), dim3(256), 0, stream>>>(w4b, b_b4, pxb, catb, 512, 384);
    k_gemm<<<dim3(32, 1, 8), dim3(256), 0, stream>>>(wpb, b_b1, xbT, catb, 512, 0);
    k_gemm<<<dim3(32, 1, 8), dim3(256), 0, stream>>>(wpb + 128 * 512, b_b21, xbT, t2b, 128, 0);
    k_gemm<<<dim3(32, 1, 8), dim3(256), 0, stream>>>(wpb + 256 * 512, b_b31, xbT, t3b, 128, 0);
    k_offconv2<3, 18><<<dim3(32, 1, 8), dim3(512), 0, stream>>>(t2b, wo2t, b_off2, off2);
    k_offconv2<5, 50><<<dim3(32, 1, 8), dim3(512), 0, stream>>>(t3b, wo3t, b_off3, off3);
    k_deform6<3><<<dim3(64, 1, 8), dim3(512), 0, stream>>>(t2b, off2, wd2t, b_ddc2, catb, 128);
    k_deform6<5><<<dim3(64, 1, 8), dim3(512), 0, stream>>>(t3b, off3, wd3t, b_ddc3, catb, 256);
    k_gemm_final<<<dim3(32, 4, 8), dim3(256), 0, stream>>>(wccb, b_cc, catb, xbT, x, out);
}

// Round 3
// 555.194 us; speedup vs baseline: 1.4416x; 1.0868x over previous
//
#include <hip/hip_runtime.h>
#include <math.h>

#define HW 4096
typedef short short8 __attribute__((ext_vector_type(8)));
typedef float floatx4 __attribute__((ext_vector_type(4)));

// ---- ws layout (bytes) ----
#define O_XBT   0ull            // [8][4096][512] bf16 x NHWC
#define O_PXB   33554432ull     // [8][4096][512] bf16 pooled x NHWC (reused later)
#define O_CATB  67108864ull     // [8][4096][512] bf16 cat branches NHWC
#define O_WPB   100663296ull    // [384][512] bf16
#define O_W4B   101056512ull    // [128][512] bf16
#define O_WCCB  101187584ull    // [512][512] bf16
#define O_WD2T  101711872ull    // [9][128][128] bf16 (t,o,c)
#define O_WD3T  102006784ull    // [25][128][128] bf16 (t,o,c)
#define O_WO2T  102825984ull    // [9][64][128] bf16 (t,o,c)
#define O_WO3T  102973440ull    // [25][64][128] bf16 (t,o,c)
// reuse of PXB region after b4 GEMM:
#define O_T2B   33554432ull     // [8][4096][128] bf16 b2i NHWC
#define O_T3B   41943040ull     // [8][4096][128] bf16 b3i NHWC
#define O_OFF2  50331648ull     // [8][18][4096] f32
#define O_OFF3  52690944ull     // [8][50][4096] f32

__device__ __forceinline__ unsigned short f2b(float f) {
    union { float f; unsigned u; } v; v.f = f;
    unsigned r = v.u + 0x7FFFu + ((v.u >> 16) & 1u);
    return (unsigned short)(r >> 16);
}
__device__ __forceinline__ float lou(unsigned u) {
    union { unsigned u; float f; } v; v.u = u << 16; return v.f;
}
__device__ __forceinline__ float hiu(unsigned u) {
    union { unsigned u; float f; } v; v.u = u & 0xFFFF0000u; return v.f;
}
__device__ __forceinline__ unsigned pk2(float lo, float hi) {
    return (unsigned)f2b(lo) | ((unsigned)f2b(hi) << 16);
}

// ------------------------------------------------------------- weight prep
__global__ __launch_bounds__(256) void k_prepw(
        const float* __restrict__ w1, const float* __restrict__ w21,
        const float* __restrict__ w31, const float* __restrict__ w4,
        const float* __restrict__ wcc, const float* __restrict__ wd2,
        const float* __restrict__ wd3, const float* __restrict__ wo2,
        const float* __restrict__ wo3, unsigned short* __restrict__ ws8) {
    unsigned i = blockIdx.x * 256 + threadIdx.x;
    unsigned short* wpb  = ws8 + (O_WPB  >> 1);
    unsigned short* w4b  = ws8 + (O_W4B  >> 1);
    unsigned short* wccb = ws8 + (O_WCCB >> 1);
    unsigned short* wd2t = ws8 + (O_WD2T >> 1);
    unsigned short* wd3t = ws8 + (O_WD3T >> 1);
    unsigned short* wo2t = ws8 + (O_WO2T >> 1);
    unsigned short* wo3t = ws8 + (O_WO3T >> 1);
    if (i < 196608) {
        int o = i >> 9;
        float v = (o < 128) ? w1[i] : (o < 256) ? w21[i - 65536] : w31[i - 131072];
        wpb[i] = f2b(v);
    } else if (i < 262144) {
        unsigned j = i - 196608; w4b[j] = f2b(w4[j]);
    } else if (i < 524288) {
        unsigned j = i - 262144; wccb[j] = f2b(wcc[j]);
    } else if (i < 671744) {
        unsigned j = i - 524288; int t = j >> 14, o = (j >> 7) & 127, c = j & 127;
        wd2t[j] = f2b(wd2[((o * 128 + c) * 9) + t]);
    } else if (i < 1081344) {
        unsigned j = i - 671744; int t = j >> 14, o = (j >> 7) & 127, c = j & 127;
        wd3t[j] = f2b(wd3[((o * 128 + c) * 25) + t]);
    } else if (i < 1155072) {
        // layout (t, o, c): j = (t*64 + o)*128 + c
        unsigned j = i - 1081344; int t = j >> 13, o = (j >> 7) & 63, c = j & 127;
        wo2t[j] = (o < 18) ? f2b(wo2[((o * 128 + c) * 9) + t]) : 0;
    } else if (i < 1359872) {
        unsigned j = i - 1155072; int t = j >> 13, o = (j >> 7) & 63, c = j & 127;
        wo3t[j] = (o < 50) ? f2b(wo3[((o * 128 + c) * 25) + t]) : 0;
    }
}

// ---------------------------------------- x NCHW f32 -> NHWC bf16 transpose
__global__ __launch_bounds__(256) void k_xpose(const float* __restrict__ X,
                                               unsigned short* __restrict__ xbT) {
    __shared__ unsigned short t[32][33];
    const int p0 = blockIdx.x * 32, c0 = blockIdx.y * 32, b = blockIdx.z;
    const int tid = threadIdx.x;
    #pragma unroll
    for (int s = 0; s < 4; ++s) {
        int cl = s * 8 + (tid >> 5), pl = tid & 31;
        t[cl][pl] = f2b(X[((size_t)b * 512 + c0 + cl) * HW + p0 + pl]);
    }
    __syncthreads();
    #pragma unroll
    for (int s = 0; s < 4; ++s) {
        int pl = s * 8 + (tid >> 5), cl = tid & 31;
        xbT[((size_t)b * HW + p0 + pl) * 512 + c0 + cl] = t[cl][pl];
    }
}

// ----------------------------------------------- 3x3 s1 maxpool on NHWC bf16
__global__ __launch_bounds__(256) void k_pool(const unsigned short* __restrict__ xbT,
                                              unsigned short* __restrict__ pxb) {
    unsigned gid = blockIdx.x * 256 + threadIdx.x;   // 8*4096*64
    int b = gid >> 18;
    unsigned rem = gid & 262143;
    int pos = rem >> 6;
    int cg = (rem & 63) * 8;
    int h = pos >> 6, w = pos & 63;
    const unsigned short* img = xbT + (size_t)b * HW * 512;
    float m[8] = {-INFINITY, -INFINITY, -INFINITY, -INFINITY,
                  -INFINITY, -INFINITY, -INFINITY, -INFINITY};
    #pragma unroll
    for (int dy = -1; dy <= 1; ++dy) {
        int hh = h + dy;
        if (hh < 0 || hh >= 64) continue;
        #pragma unroll
        for (int dx = -1; dx <= 1; ++dx) {
            int ww = w + dx;
            if (ww < 0 || ww >= 64) continue;
            uint4 v = *(const uint4*)(img + ((size_t)(hh * 64 + ww)) * 512 + cg);
            unsigned uu[4] = {v.x, v.y, v.z, v.w};
            #pragma unroll
            for (int e = 0; e < 4; ++e) {
                m[2 * e]     = fmaxf(m[2 * e],     lou(uu[e]));
                m[2 * e + 1] = fmaxf(m[2 * e + 1], hiu(uu[e]));
            }
        }
    }
    uint4 o;
    o.x = pk2(m[0], m[1]); o.y = pk2(m[2], m[3]);
    o.z = pk2(m[4], m[5]); o.w = pk2(m[6], m[7]);
    *(uint4*)(pxb + ((size_t)b * HW + pos) * 512 + cg) = o;
}

// ----------------------------- bf16 MFMA GEMM: C[128 x 128pos] = A[128x512]B
#define SA(r,c) SM[(r)*40 + (c)]
#define SB(r,c) SM[5120 + (r)*40 + (c)]
#define SC(r,c) SM[(r)*136 + (c)]
__global__ __launch_bounds__(256) void k_gemm(
        const unsigned short* __restrict__ A, const float* __restrict__ bias,
        const unsigned short* __restrict__ Bm,
        unsigned short* __restrict__ dst, int dStride, int dOff) {
    __shared__ unsigned short SM[17408];
    const int tid = threadIdx.x;
    const int n0 = blockIdx.x * 128;
    const int b = blockIdx.z;
    const int wave = tid >> 6, lane = tid & 63, quad = lane >> 4, lr = lane & 15;
    const int m0w = (wave & 1) * 64, n0w = (wave >> 1) * 64;
    const int srow = tid >> 1, skh = (tid & 1) * 16;
    floatx4 acc[4][4] = {};

    for (int k0 = 0; k0 < 512; k0 += 32) {
        const unsigned short* ga = A + (size_t)srow * 512 + k0 + skh;
        uint4 a0 = *(const uint4*)(ga);
        uint4 a1 = *(const uint4*)(ga + 8);
        const unsigned short* gb = Bm + ((size_t)b * HW + n0 + srow) * 512 + k0 + skh;
        uint4 b0 = *(const uint4*)(gb);
        uint4 b1 = *(const uint4*)(gb + 8);
        __syncthreads();
        *(uint4*)&SA(srow, skh) = a0;
        *(uint4*)&SA(srow, skh + 8) = a1;
        *(uint4*)&SB(srow, skh) = b0;
        *(uint4*)&SB(srow, skh + 8) = b1;
        __syncthreads();
        short8 af[4], bf[4];
        #pragma unroll
        for (int i = 0; i < 4; ++i) af[i] = *(short8*)&SA(m0w + i * 16 + lr, quad * 8);
        #pragma unroll
        for (int j = 0; j < 4; ++j) bf[j] = *(short8*)&SB(n0w + j * 16 + lr, quad * 8);
        #pragma unroll
        for (int i = 0; i < 4; ++i)
            #pragma unroll
            for (int j = 0; j < 4; ++j)
                acc[i][j] = __builtin_amdgcn_mfma_f32_16x16x32_bf16(af[i], bf[j], acc[i][j], 0, 0, 0);
    }
    __syncthreads();
    #pragma unroll
    for (int i = 0; i < 4; ++i) {
        float4 bs = *(const float4*)&bias[m0w + i * 16 + quad * 4];
        #pragma unroll
        for (int j = 0; j < 4; ++j) {
            floatx4 v = acc[i][j];
            int pos = n0w + j * 16 + lr;
            int ch = m0w + i * 16 + quad * 4;
            uint2 st;
            st.x = pk2(v[0] + bs.x, v[1] + bs.y);
            st.y = pk2(v[2] + bs.z, v[3] + bs.w);
            *(uint2*)&SC(pos, ch) = st;
        }
    }
    __syncthreads();
    #pragma unroll
    for (int r = 0; r < 8; ++r) {
        int pos = (tid >> 4) + r * 16;
        *(uint4*)&dst[((size_t)b * HW + n0 + pos) * dStride + dOff + (tid & 15) * 8] =
            *(uint4*)&SC(pos, (tid & 15) * 8);
    }
}

// ---------------- offset convs v2: slab-staged, barrier-free tap loop
// block = 128 positions (2 h-rows) x 64 M (padded), 512 threads.
template<int KS, int OCH>
__global__ __launch_bounds__(512) void k_offconv2(
        const unsigned short* __restrict__ img,   // [B][4096][128] bf16
        const unsigned short* __restrict__ woT,   // [TT][64][128] bf16 (t,o,c)
        const float* __restrict__ bias, float* __restrict__ Out) {
    constexpr int PAD = KS / 2;
    constexpr int TT = KS * KS;
    constexpr int SR = 2 + 2 * PAD;
    constexpr int SC2 = 64 + 2 * PAD;
    constexpr int NE = SR * SC2;              // slab entries
    __shared__ unsigned short slab[NE * 36];  // [entry][36] (32 ch + pad)
    __shared__ float ctile[64 * 132];
    const int tid = threadIdx.x;
    const int p0 = blockIdx.x * 128, hrow0 = blockIdx.x * 2, b = blockIdx.z;
    const int wave = tid >> 6, lane = tid & 63, quad = lane >> 4, lr = lane & 15;
    const int wm = wave & 1, wn = wave >> 1;   // 2 x 4 wave grid: 32o x 32pos
    const unsigned short* ib = img + (size_t)b * HW * 128;
    floatx4 acc[2][2] = {};

    for (int c0 = 0; c0 < 128; c0 += 32) {
        __syncthreads();
        if (tid < NE) {
            int s = tid / SC2, cl = tid % SC2;
            int r = hrow0 - PAD + s, cc = cl - PAD;
            uint4 v0 = {}, v1 = {}, v2 = {}, v3 = {};
            if ((unsigned)r < 64u && (unsigned)cc < 64u) {
                const uint4* g = (const uint4*)(ib + ((size_t)(r * 64 + cc)) * 128 + c0);
                v0 = g[0]; v1 = g[1]; v2 = g[2]; v3 = g[3];
            }
            uint2* d2 = (uint2*)&slab[tid * 36];
            d2[0] = make_uint2(v0.x, v0.y); d2[1] = make_uint2(v0.z, v0.w);
            d2[2] = make_uint2(v1.x, v1.y); d2[3] = make_uint2(v1.z, v1.w);
            d2[4] = make_uint2(v2.x, v2.y); d2[5] = make_uint2(v2.z, v2.w);
            d2[6] = make_uint2(v3.x, v3.y); d2[7] = make_uint2(v3.z, v3.w);
        }
        __syncthreads();
        #pragma unroll
        for (int t = 0; t < TT; ++t) {
            const int ky = t / KS, kx = t % KS;
            short8 af[2], bf[2];
            #pragma unroll
            for (int i = 0; i < 2; ++i)
                af[i] = *(const short8*)&woT[((size_t)t * 64 + wm * 32 + i * 16 + lr) * 128
                                             + c0 + quad * 8];
            #pragma unroll
            for (int j = 0; j < 2; ++j) {
                int p = wn * 32 + j * 16 + lr;
                int e = ((p >> 6) + ky) * SC2 + (p & 63) + kx;
                union { uint2 u[2]; short8 s; } bb;
                const uint2* sp = (const uint2*)&slab[e * 36 + quad * 8];
                bb.u[0] = sp[0]; bb.u[1] = sp[1];
                bf[j] = bb.s;
            }
            #pragma unroll
            for (int i = 0; i < 2; ++i)
                #pragma unroll
                for (int j = 0; j < 2; ++j)
                    acc[i][j] = __builtin_amdgcn_mfma_f32_16x16x32_bf16(af[i], bf[j], acc[i][j], 0, 0, 0);
        }
    }
    __syncthreads();
    #pragma unroll
    for (int i = 0; i < 2; ++i)
        #pragma unroll
        for (int j = 0; j < 2; ++j) {
            floatx4 v = acc[i][j];
            int p = wn * 32 + j * 16 + lr;
            int o = wm * 32 + i * 16 + quad * 4;
            #pragma unroll
            for (int rg = 0; rg < 4; ++rg)
                ctile[(o + rg) * 132 + p] = v[rg];
        }
    __syncthreads();
    {
        int o = tid >> 3, seg = tid & 7;
        if (o < OCH) {
            float bs = bias[o];
            const float* src = &ctile[o * 132 + seg * 16];
            float* dst = &Out[((size_t)b * OCH + o) * HW + p0 + seg * 16];
            #pragma unroll
            for (int q = 0; q < 4; ++q) {
                float4 v = *(const float4*)(src + q * 4);
                v.x += bs; v.y += bs; v.z += bs; v.w += bs;
                *(float4*)(dst + q * 4) = v;
            }
        }
    }
}

// ---------------------- deformable conv v7: spill-free, direct-weight MFMA
// block = 512 threads (8 waves), tile = 128 o x 64 pos, grid = 64 x 8.
// launch_bounds(512,4): 2 blocks/CU target -> VGPR cap 128 (not 64) -> no spill.
// Weights read directly from L2-resident wdT (k_offconv2 pattern); LDS = sS only.
template<int KS>
__global__ __launch_bounds__(512, 4) void k_deform7(
        const unsigned short* __restrict__ img,   // [B][4096][128] bf16
        const float* __restrict__ Off,            // [B][2TT][4096] f32
        const unsigned short* __restrict__ wdT,   // [TT][128][128] bf16 (t,o,c)
        const float* __restrict__ bias,
        unsigned short* __restrict__ catb, int dOff) {
    constexpr int PAD = KS / 2;
    constexpr int TT = KS * KS;
    __shared__ unsigned short sS[64][136];    // samples [pos][c], +8 pad
    const int tid = threadIdx.x;
    const int b = blockIdx.z;
    const int p0 = blockIdx.x * 64;           // one h-row per block
    const int wave = tid >> 6, lane = tid & 63, quad = lane >> 4, lr = lane & 15;
    const int m0w = (wave & 3) * 32;          // 4 m-waves x 32 o
    const int n0w = (wave >> 2) * 32;         // 2 n-waves x 32 pos
    const int pos = tid >> 3;                 // 0..63
    const int cseg = (tid & 7) * 16;          // 16-ch segment
    const int pglob = p0 + pos;
    const int h = blockIdx.x, w = pos;
    const unsigned short* ib = img + (size_t)b * HW * 128;
    const float* offb = Off + (size_t)b * 2 * TT * HW;
    floatx4 acc[2][2] = {};

    for (int t = 0; t < TT; ++t) {
        float dy = offb[(size_t)(2 * t) * HW + pglob];
        float dx = offb[(size_t)(2 * t + 1) * HW + pglob];
        float fy = (float)(h + t / KS - PAD) + dy;
        float fx = (float)(w + t % KS - PAD) + dx;
        float y0f = floorf(fy), x0f = floorf(fx);
        float wy = fy - y0f, wx = fx - x0f;
        int y0 = (int)y0f, x0 = (int)x0f;
        float w00 = (1.f - wy) * (1.f - wx), w01 = (1.f - wy) * wx;
        float w10 = wy * (1.f - wx), w11 = wy * wx;
        bool yv0 = (unsigned)y0 < 64u, yv1 = (unsigned)(y0 + 1) < 64u;
        bool xv0 = (unsigned)x0 < 64u, xv1 = (unsigned)(x0 + 1) < 64u;
        uint4 cA[2] = {}, cB[2] = {}, cC[2] = {}, cD[2] = {};
        long bidx = (long)(y0 * 64 + x0) * 128 + cseg;
        if (yv0 && xv0) { const uint4* p = (const uint4*)(ib + bidx);
            cA[0] = p[0]; cA[1] = p[1]; }
        if (yv0 && xv1) { const uint4* p = (const uint4*)(ib + bidx + 128);
            cB[0] = p[0]; cB[1] = p[1]; }
        if (yv1 && xv0) { const uint4* p = (const uint4*)(ib + bidx + 8192);
            cC[0] = p[0]; cC[1] = p[1]; }
        if (yv1 && xv1) { const uint4* p = (const uint4*)(ib + bidx + 8320);
            cD[0] = p[0]; cD[1] = p[1]; }
        uint4 outv[2];
        #pragma unroll
        for (int j = 0; j < 2; ++j) {
            unsigned a[4] = {cA[j].x, cA[j].y, cA[j].z, cA[j].w};
            unsigned bb[4] = {cB[j].x, cB[j].y, cB[j].z, cB[j].w};
            unsigned c[4] = {cC[j].x, cC[j].y, cC[j].z, cC[j].w};
            unsigned d[4] = {cD[j].x, cD[j].y, cD[j].z, cD[j].w};
            unsigned r[4];
            #pragma unroll
            for (int e = 0; e < 4; ++e) {
                float lo = w00 * lou(a[e]) + w01 * lou(bb[e]) + w10 * lou(c[e]) + w11 * lou(d[e]);
                float hi = w00 * hiu(a[e]) + w01 * hiu(bb[e]) + w10 * hiu(c[e]) + w11 * hiu(d[e]);
                r[e] = pk2(lo, hi);
            }
            outv[j].x = r[0]; outv[j].y = r[1]; outv[j].z = r[2]; outv[j].w = r[3];
        }
        __syncthreads();
        *(uint4*)&sS[pos][cseg] = outv[0];
        *(uint4*)&sS[pos][cseg + 8] = outv[1];
        __syncthreads();
        const unsigned short* wt = wdT + (size_t)t * 128 * 128;
        #pragma unroll
        for (int ks = 0; ks < 4; ++ks) {
            short8 af[2], bf[2];
            #pragma unroll
            for (int i = 0; i < 2; ++i)
                af[i] = *(const short8*)&wt[(size_t)(m0w + i * 16 + lr) * 128
                                            + ks * 32 + quad * 8];
            #pragma unroll
            for (int j = 0; j < 2; ++j)
                bf[j] = *(short8*)&sS[n0w + j * 16 + lr][ks * 32 + quad * 8];
            #pragma unroll
            for (int i = 0; i < 2; ++i)
                #pragma unroll
                for (int j = 0; j < 2; ++j)
                    acc[i][j] = __builtin_amdgcn_mfma_f32_16x16x32_bf16(af[i], bf[j], acc[i][j], 0, 0, 0);
        }
    }
    // epilogue: bias + bf16 pack via sS, coalesced store to catb
    __syncthreads();
    #pragma unroll
    for (int i = 0; i < 2; ++i) {
        float4 bs = *(const float4*)&bias[m0w + i * 16 + quad * 4];
        #pragma unroll
        for (int j = 0; j < 2; ++j) {
            floatx4 v = acc[i][j];
            int p = n0w + j * 16 + lr;
            int ch = m0w + i * 16 + quad * 4;
            uint2 st;
            st.x = pk2(v[0] + bs.x, v[1] + bs.y);
            st.y = pk2(v[2] + bs.z, v[3] + bs.w);
            *(uint2*)&sS[p][ch] = st;
        }
    }
    __syncthreads();
    #pragma unroll
    for (int r = 0; r < 2; ++r) {
        int idx = r * 512 + tid;
        int p = idx >> 4, sg = (idx & 15) * 8;
        *(uint4*)&catb[((size_t)b * HW + p0 + p) * 512 + dOff + sg] =
            *(uint4*)&sS[p][sg];
    }
}

// ------------------- final: sigmoid(Wcc @ (catb*xbT)) + x, fp32 NCHW output
__global__ __launch_bounds__(256) void k_gemm_final(
        const unsigned short* __restrict__ A, const float* __restrict__ bias,
        const unsigned short* __restrict__ catb, const unsigned short* __restrict__ xbT,
        const float* __restrict__ X, float* __restrict__ OutF) {
    __shared__ unsigned short sA[128][40];
    __shared__ unsigned short sB[128][40];
    const int tid = threadIdx.x;
    const int n0 = blockIdx.x * 128;
    const int o0 = blockIdx.y * 128;
    const int b = blockIdx.z;
    const int wave = tid >> 6, lane = tid & 63, quad = lane >> 4, lr = lane & 15;
    const int m0w = (wave & 1) * 64, n0w = (wave >> 1) * 64;
    const int srow = tid >> 1, skh = (tid & 1) * 16;
    floatx4 acc[4][4] = {};

    for (int k0 = 0; k0 < 512; k0 += 32) {
        const unsigned short* ga = A + (size_t)(o0 + srow) * 512 + k0 + skh;
        uint4 a0 = *(const uint4*)(ga);
        uint4 a1 = *(const uint4*)(ga + 8);
        size_t bi = ((size_t)b * HW + n0 + srow) * 512 + k0 + skh;
        uint4 c0 = *(const uint4*)(catb + bi);
        uint4 c1 = *(const uint4*)(catb + bi + 8);
        uint4 x0 = *(const uint4*)(xbT + bi);
        uint4 x1 = *(const uint4*)(xbT + bi + 8);
        unsigned cu[8] = {c0.x, c0.y, c0.z, c0.w, c1.x, c1.y, c1.z, c1.w};
        unsigned xu[8] = {x0.x, x0.y, x0.z, x0.w, x1.x, x1.y, x1.z, x1.w};
        unsigned mu[8];
        #pragma unroll
        for (int e = 0; e < 8; ++e)
            mu[e] = pk2(lou(cu[e]) * lou(xu[e]), hiu(cu[e]) * hiu(xu[e]));
        __syncthreads();
        *(uint4*)&sA[srow][skh] = a0;
        *(uint4*)&sA[srow][skh + 8] = a1;
        uint4 m0v; m0v.x = mu[0]; m0v.y = mu[1]; m0v.z = mu[2]; m0v.w = mu[3];
        uint4 m1v; m1v.x = mu[4]; m1v.y = mu[5]; m1v.z = mu[6]; m1v.w = mu[7];
        *(uint4*)&sB[srow][skh] = m0v;
        *(uint4*)&sB[srow][skh + 8] = m1v;
        __syncthreads();
        short8 af[4], bf[4];
        #pragma unroll
        for (int i = 0; i < 4; ++i) af[i] = *(short8*)&sA[m0w + i * 16 + lr][quad * 8];
        #pragma unroll
        for (int j = 0; j < 4; ++j) bf[j] = *(short8*)&sB[n0w + j * 16 + lr][quad * 8];
        #pragma unroll
        for (int i = 0; i < 4; ++i)
            #pragma unroll
            for (int j = 0; j < 4; ++j)
                acc[i][j] = __builtin_amdgcn_mfma_f32_16x16x32_bf16(af[i], bf[j], acc[i][j], 0, 0, 0);
    }
    #pragma unroll
    for (int i = 0; i < 4; ++i) {
        float4 bs = *(const float4*)&bias[o0 + m0w + i * 16 + quad * 4];
        float bsa[4] = {bs.x, bs.y, bs.z, bs.w};
        #pragma unroll
        for (int j = 0; j < 4; ++j) {
            floatx4 v = acc[i][j];
            int pos = n0 + n0w + j * 16 + lr;
            #pragma unroll
            for (int rg = 0; rg < 4; ++rg) {
                int o = o0 + m0w + i * 16 + quad * 4 + rg;
                float f = v[rg] + bsa[rg];
                float sg = 1.f / (1.f + __expf(-f));
                size_t idx = ((size_t)b * 512 + o) * HW + pos;
                OutF[idx] = X[idx] + sg;
            }
        }
    }
}

// ------------------------------------------------------------------- launcher
extern "C" void kernel_launch(void* const* d_in, const int* in_sizes, int n_in,
                              void* d_out, int out_size, void* d_ws, size_t ws_size,
                              hipStream_t stream) {
    const float* x      = (const float*)d_in[0];
    const float* w_b1   = (const float*)d_in[1];
    const float* b_b1   = (const float*)d_in[2];
    const float* w_b21  = (const float*)d_in[3];
    const float* b_b21  = (const float*)d_in[4];
    const float* w_off2 = (const float*)d_in[5];
    const float* b_off2 = (const float*)d_in[6];
    const float* w_ddc2 = (const float*)d_in[7];
    const float* b_ddc2 = (const float*)d_in[8];
    const float* w_b31  = (const float*)d_in[9];
    const float* b_b31  = (const float*)d_in[10];
    const float* w_off3 = (const float*)d_in[11];
    const float* b_off3 = (const float*)d_in[12];
    const float* w_ddc3 = (const float*)d_in[13];
    const float* b_ddc3 = (const float*)d_in[14];
    const float* w_b4   = (const float*)d_in[15];
    const float* b_b4   = (const float*)d_in[16];
    const float* w_cc   = (const float*)d_in[17];
    const float* b_cc   = (const float*)d_in[18];

    char* wsb = (char*)d_ws;
    unsigned short* ws8  = (unsigned short*)d_ws;
    unsigned short* xbT  = (unsigned short*)(wsb + O_XBT);
    unsigned short* pxb  = (unsigned short*)(wsb + O_PXB);
    unsigned short* catb = (unsigned short*)(wsb + O_CATB);
    unsigned short* wpb  = (unsigned short*)(wsb + O_WPB);
    unsigned short* w4b  = (unsigned short*)(wsb + O_W4B);
    unsigned short* wccb = (unsigned short*)(wsb + O_WCCB);
    unsigned short* wd2t = (unsigned short*)(wsb + O_WD2T);
    unsigned short* wd3t = (unsigned short*)(wsb + O_WD3T);
    unsigned short* wo2t = (unsigned short*)(wsb + O_WO2T);
    unsigned short* wo3t = (unsigned short*)(wsb + O_WO3T);
    unsigned short* t2b  = (unsigned short*)(wsb + O_T2B);
    unsigned short* t3b  = (unsigned short*)(wsb + O_T3B);
    float* off2 = (float*)(wsb + O_OFF2);
    float* off3 = (float*)(wsb + O_OFF3);
    float* out  = (float*)d_out;

    k_prepw<<<dim3(5312), dim3(256), 0, stream>>>(
        w_b1, w_b21, w_b31, w_b4, w_cc, w_ddc2, w_ddc3, w_off2, w_off3, ws8);
    k_xpose<<<dim3(128, 16, 8), dim3(256), 0, stream>>>(x, xbT);
    k_pool<<<dim3(8192), dim3(256), 0, stream>>>(xbT, pxb);
    // b4 first (frees pxb region for t2b/t3b/offsets)
    k_gemm<<<dim3(32, 1, 8), dim3(256), 0, stream>>>(w4b, b_b4, pxb, catb, 512, 384);
    k_gemm<<<dim3(32, 1, 8), dim3(256), 0, stream>>>(wpb, b_b1, xbT, catb, 512, 0);
    k_gemm<<<dim3(32, 1, 8), dim3(256), 0, stream>>>(wpb + 128 * 512, b_b21, xbT, t2b, 128, 0);
    k_gemm<<<dim3(32, 1, 8), dim3(256), 0, stream>>>(wpb + 256 * 512, b_b31, xbT, t3b, 128, 0);
    k_offconv2<3, 18><<<dim3(32, 1, 8), dim3(512), 0, stream>>>(t2b, wo2t, b_off2, off2);
    k_offconv2<5, 50><<<dim3(32, 1, 8), dim3(512), 0, stream>>>(t3b, wo3t, b_off3, off3);
    k_deform7<3><<<dim3(64, 1, 8), dim3(512), 0, stream>>>(t2b, off2, wd2t, b_ddc2, catb, 128);
    k_deform7<5><<<dim3(64, 1, 8), dim3(512), 0, stream>>>(t3b, off3, wd3t, b_ddc3, catb, 256);
    k_gemm_final<<<dim3(32, 4, 8), dim3(256), 0, stream>>>(wccb, b_cc, catb, xbT, x, out);
}

// Round 4
// 554.482 us; speedup vs baseline: 1.4434x; 1.0013x over previous
//
#include <hip/hip_runtime.h>
#include <math.h>

#define HW 4096
typedef short short8 __attribute__((ext_vector_type(8)));
typedef float floatx4 __attribute__((ext_vector_type(4)));

// ---- ws layout (bytes) ----
#define O_XBT   0ull            // [8][4096][512] bf16 x NHWC
#define O_PXB   33554432ull     // [8][4096][512] bf16 pooled x NHWC (reused later)
#define O_CATB  67108864ull     // [8][4096][512] bf16 cat branches NHWC
#define O_WPB   100663296ull    // [384][512] bf16
#define O_W4B   101056512ull    // [128][512] bf16
#define O_WCCB  101187584ull    // [512][512] bf16
#define O_WD2T  101711872ull    // [9][128][128] bf16 (t,o,c)
#define O_WD3T  102006784ull    // [25][128][128] bf16 (t,o,c)
#define O_WO2T  102825984ull    // [9][64][128] bf16 (t,o,c)
#define O_WO3T  102973440ull    // [25][64][128] bf16 (t,o,c)
// reuse of PXB region after b4 GEMM:
#define O_T2B   33554432ull     // [8][4096][128] bf16 b2i NHWC
#define O_T3B   41943040ull     // [8][4096][128] bf16 b3i NHWC
#define O_OFF2  50331648ull     // [8][18][4096] f32
#define O_OFF3  52690944ull     // [8][50][4096] f32

__device__ __forceinline__ unsigned short f2b(float f) {
    union { float f; unsigned u; } v; v.f = f;
    unsigned r = v.u + 0x7FFFu + ((v.u >> 16) & 1u);
    return (unsigned short)(r >> 16);
}
__device__ __forceinline__ float lou(unsigned u) {
    union { unsigned u; float f; } v; v.u = u << 16; return v.f;
}
__device__ __forceinline__ float hiu(unsigned u) {
    union { unsigned u; float f; } v; v.u = u & 0xFFFF0000u; return v.f;
}
__device__ __forceinline__ unsigned pk2(float lo, float hi) {
    return (unsigned)f2b(lo) | ((unsigned)f2b(hi) << 16);
}

// ------------------------------------------------------------- weight prep
__global__ __launch_bounds__(256) void k_prepw(
        const float* __restrict__ w1, const float* __restrict__ w21,
        const float* __restrict__ w31, const float* __restrict__ w4,
        const float* __restrict__ wcc, const float* __restrict__ wd2,
        const float* __restrict__ wd3, const float* __restrict__ wo2,
        const float* __restrict__ wo3, unsigned short* __restrict__ ws8) {
    unsigned i = blockIdx.x * 256 + threadIdx.x;
    unsigned short* wpb  = ws8 + (O_WPB  >> 1);
    unsigned short* w4b  = ws8 + (O_W4B  >> 1);
    unsigned short* wccb = ws8 + (O_WCCB >> 1);
    unsigned short* wd2t = ws8 + (O_WD2T >> 1);
    unsigned short* wd3t = ws8 + (O_WD3T >> 1);
    unsigned short* wo2t = ws8 + (O_WO2T >> 1);
    unsigned short* wo3t = ws8 + (O_WO3T >> 1);
    if (i < 196608) {
        int o = i >> 9;
        float v = (o < 128) ? w1[i] : (o < 256) ? w21[i - 65536] : w31[i - 131072];
        wpb[i] = f2b(v);
    } else if (i < 262144) {
        unsigned j = i - 196608; w4b[j] = f2b(w4[j]);
    } else if (i < 524288) {
        unsigned j = i - 262144; wccb[j] = f2b(wcc[j]);
    } else if (i < 671744) {
        unsigned j = i - 524288; int t = j >> 14, o = (j >> 7) & 127, c = j & 127;
        wd2t[j] = f2b(wd2[((o * 128 + c) * 9) + t]);
    } else if (i < 1081344) {
        unsigned j = i - 671744; int t = j >> 14, o = (j >> 7) & 127, c = j & 127;
        wd3t[j] = f2b(wd3[((o * 128 + c) * 25) + t]);
    } else if (i < 1155072) {
        // layout (t, o, c): j = (t*64 + o)*128 + c
        unsigned j = i - 1081344; int t = j >> 13, o = (j >> 7) & 63, c = j & 127;
        wo2t[j] = (o < 18) ? f2b(wo2[((o * 128 + c) * 9) + t]) : 0;
    } else if (i < 1359872) {
        unsigned j = i - 1155072; int t = j >> 13, o = (j >> 7) & 63, c = j & 127;
        wo3t[j] = (o < 50) ? f2b(wo3[((o * 128 + c) * 25) + t]) : 0;
    }
}

// ---------------------------------------- x NCHW f32 -> NHWC bf16 transpose
__global__ __launch_bounds__(256) void k_xpose(const float* __restrict__ X,
                                               unsigned short* __restrict__ xbT) {
    __shared__ unsigned short t[32][33];
    const int p0 = blockIdx.x * 32, c0 = blockIdx.y * 32, b = blockIdx.z;
    const int tid = threadIdx.x;
    #pragma unroll
    for (int s = 0; s < 4; ++s) {
        int cl = s * 8 + (tid >> 5), pl = tid & 31;
        t[cl][pl] = f2b(X[((size_t)b * 512 + c0 + cl) * HW + p0 + pl]);
    }
    __syncthreads();
    #pragma unroll
    for (int s = 0; s < 4; ++s) {
        int pl = s * 8 + (tid >> 5), cl = tid & 31;
        xbT[((size_t)b * HW + p0 + pl) * 512 + c0 + cl] = t[cl][pl];
    }
}

// ----------------------------------------------- 3x3 s1 maxpool on NHWC bf16
__global__ __launch_bounds__(256) void k_pool(const unsigned short* __restrict__ xbT,
                                              unsigned short* __restrict__ pxb) {
    unsigned gid = blockIdx.x * 256 + threadIdx.x;   // 8*4096*64
    int b = gid >> 18;
    unsigned rem = gid & 262143;
    int pos = rem >> 6;
    int cg = (rem & 63) * 8;
    int h = pos >> 6, w = pos & 63;
    const unsigned short* img = xbT + (size_t)b * HW * 512;
    float m[8] = {-INFINITY, -INFINITY, -INFINITY, -INFINITY,
                  -INFINITY, -INFINITY, -INFINITY, -INFINITY};
    #pragma unroll
    for (int dy = -1; dy <= 1; ++dy) {
        int hh = h + dy;
        if (hh < 0 || hh >= 64) continue;
        #pragma unroll
        for (int dx = -1; dx <= 1; ++dx) {
            int ww = w + dx;
            if (ww < 0 || ww >= 64) continue;
            uint4 v = *(const uint4*)(img + ((size_t)(hh * 64 + ww)) * 512 + cg);
            unsigned uu[4] = {v.x, v.y, v.z, v.w};
            #pragma unroll
            for (int e = 0; e < 4; ++e) {
                m[2 * e]     = fmaxf(m[2 * e],     lou(uu[e]));
                m[2 * e + 1] = fmaxf(m[2 * e + 1], hiu(uu[e]));
            }
        }
    }
    uint4 o;
    o.x = pk2(m[0], m[1]); o.y = pk2(m[2], m[3]);
    o.z = pk2(m[4], m[5]); o.w = pk2(m[6], m[7]);
    *(uint4*)(pxb + ((size_t)b * HW + pos) * 512 + cg) = o;
}

// ----------------------------- bf16 MFMA GEMM: C[128 x 128pos] = A[128x512]B
#define SA(r,c) SM[(r)*40 + (c)]
#define SB(r,c) SM[5120 + (r)*40 + (c)]
#define SC(r,c) SM[(r)*136 + (c)]
__global__ __launch_bounds__(256) void k_gemm(
        const unsigned short* __restrict__ A, const float* __restrict__ bias,
        const unsigned short* __restrict__ Bm,
        unsigned short* __restrict__ dst, int dStride, int dOff) {
    __shared__ unsigned short SM[17408];
    const int tid = threadIdx.x;
    const int n0 = blockIdx.x * 128;
    const int b = blockIdx.z;
    const int wave = tid >> 6, lane = tid & 63, quad = lane >> 4, lr = lane & 15;
    const int m0w = (wave & 1) * 64, n0w = (wave >> 1) * 64;
    const int srow = tid >> 1, skh = (tid & 1) * 16;
    floatx4 acc[4][4] = {};

    for (int k0 = 0; k0 < 512; k0 += 32) {
        const unsigned short* ga = A + (size_t)srow * 512 + k0 + skh;
        uint4 a0 = *(const uint4*)(ga);
        uint4 a1 = *(const uint4*)(ga + 8);
        const unsigned short* gb = Bm + ((size_t)b * HW + n0 + srow) * 512 + k0 + skh;
        uint4 b0 = *(const uint4*)(gb);
        uint4 b1 = *(const uint4*)(gb + 8);
        __syncthreads();
        *(uint4*)&SA(srow, skh) = a0;
        *(uint4*)&SA(srow, skh + 8) = a1;
        *(uint4*)&SB(srow, skh) = b0;
        *(uint4*)&SB(srow, skh + 8) = b1;
        __syncthreads();
        short8 af[4], bf[4];
        #pragma unroll
        for (int i = 0; i < 4; ++i) af[i] = *(short8*)&SA(m0w + i * 16 + lr, quad * 8);
        #pragma unroll
        for (int j = 0; j < 4; ++j) bf[j] = *(short8*)&SB(n0w + j * 16 + lr, quad * 8);
        #pragma unroll
        for (int i = 0; i < 4; ++i)
            #pragma unroll
            for (int j = 0; j < 4; ++j)
                acc[i][j] = __builtin_amdgcn_mfma_f32_16x16x32_bf16(af[i], bf[j], acc[i][j], 0, 0, 0);
    }
    __syncthreads();
    #pragma unroll
    for (int i = 0; i < 4; ++i) {
        float4 bs = *(const float4*)&bias[m0w + i * 16 + quad * 4];
        #pragma unroll
        for (int j = 0; j < 4; ++j) {
            floatx4 v = acc[i][j];
            int pos = n0w + j * 16 + lr;
            int ch = m0w + i * 16 + quad * 4;
            uint2 st;
            st.x = pk2(v[0] + bs.x, v[1] + bs.y);
            st.y = pk2(v[2] + bs.z, v[3] + bs.w);
            *(uint2*)&SC(pos, ch) = st;
        }
    }
    __syncthreads();
    #pragma unroll
    for (int r = 0; r < 8; ++r) {
        int pos = (tid >> 4) + r * 16;
        *(uint4*)&dst[((size_t)b * HW + n0 + pos) * dStride + dOff + (tid & 15) * 8] =
            *(uint4*)&SC(pos, (tid & 15) * 8);
    }
}

// ---------------- offset convs v2: slab-staged, barrier-free tap loop
// block = 128 positions (2 h-rows) x 64 M (padded), 512 threads.
template<int KS, int OCH>
__global__ __launch_bounds__(512) void k_offconv2(
        const unsigned short* __restrict__ img,   // [B][4096][128] bf16
        const unsigned short* __restrict__ woT,   // [TT][64][128] bf16 (t,o,c)
        const float* __restrict__ bias, float* __restrict__ Out) {
    constexpr int PAD = KS / 2;
    constexpr int TT = KS * KS;
    constexpr int SR = 2 + 2 * PAD;
    constexpr int SC2 = 64 + 2 * PAD;
    constexpr int NE = SR * SC2;              // slab entries
    __shared__ unsigned short slab[NE * 36];  // [entry][36] (32 ch + pad)
    __shared__ float ctile[64 * 132];
    const int tid = threadIdx.x;
    const int p0 = blockIdx.x * 128, hrow0 = blockIdx.x * 2, b = blockIdx.z;
    const int wave = tid >> 6, lane = tid & 63, quad = lane >> 4, lr = lane & 15;
    const int wm = wave & 1, wn = wave >> 1;   // 2 x 4 wave grid: 32o x 32pos
    const unsigned short* ib = img + (size_t)b * HW * 128;
    floatx4 acc[2][2] = {};

    for (int c0 = 0; c0 < 128; c0 += 32) {
        __syncthreads();
        if (tid < NE) {
            int s = tid / SC2, cl = tid % SC2;
            int r = hrow0 - PAD + s, cc = cl - PAD;
            uint4 v0 = {}, v1 = {}, v2 = {}, v3 = {};
            if ((unsigned)r < 64u && (unsigned)cc < 64u) {
                const uint4* g = (const uint4*)(ib + ((size_t)(r * 64 + cc)) * 128 + c0);
                v0 = g[0]; v1 = g[1]; v2 = g[2]; v3 = g[3];
            }
            uint2* d2 = (uint2*)&slab[tid * 36];
            d2[0] = make_uint2(v0.x, v0.y); d2[1] = make_uint2(v0.z, v0.w);
            d2[2] = make_uint2(v1.x, v1.y); d2[3] = make_uint2(v1.z, v1.w);
            d2[4] = make_uint2(v2.x, v2.y); d2[5] = make_uint2(v2.z, v2.w);
            d2[6] = make_uint2(v3.x, v3.y); d2[7] = make_uint2(v3.z, v3.w);
        }
        __syncthreads();
        #pragma unroll
        for (int t = 0; t < TT; ++t) {
            const int ky = t / KS, kx = t % KS;
            short8 af[2], bf[2];
            #pragma unroll
            for (int i = 0; i < 2; ++i)
                af[i] = *(const short8*)&woT[((size_t)t * 64 + wm * 32 + i * 16 + lr) * 128
                                             + c0 + quad * 8];
            #pragma unroll
            for (int j = 0; j < 2; ++j) {
                int p = wn * 32 + j * 16 + lr;
                int e = ((p >> 6) + ky) * SC2 + (p & 63) + kx;
                union { uint2 u[2]; short8 s; } bb;
                const uint2* sp = (const uint2*)&slab[e * 36 + quad * 8];
                bb.u[0] = sp[0]; bb.u[1] = sp[1];
                bf[j] = bb.s;
            }
            #pragma unroll
            for (int i = 0; i < 2; ++i)
                #pragma unroll
                for (int j = 0; j < 2; ++j)
                    acc[i][j] = __builtin_amdgcn_mfma_f32_16x16x32_bf16(af[i], bf[j], acc[i][j], 0, 0, 0);
        }
    }
    __syncthreads();
    #pragma unroll
    for (int i = 0; i < 2; ++i)
        #pragma unroll
        for (int j = 0; j < 2; ++j) {
            floatx4 v = acc[i][j];
            int p = wn * 32 + j * 16 + lr;
            int o = wm * 32 + i * 16 + quad * 4;
            #pragma unroll
            for (int rg = 0; rg < 4; ++rg)
                ctile[(o + rg) * 132 + p] = v[rg];
        }
    __syncthreads();
    {
        int o = tid >> 3, seg = tid & 7;
        if (o < OCH) {
            float bs = bias[o];
            const float* src = &ctile[o * 132 + seg * 16];
            float* dst = &Out[((size_t)b * OCH + o) * HW + p0 + seg * 16];
            #pragma unroll
            for (int q = 0; q < 4; ++q) {
                float4 v = *(const float4*)(src + q * 4);
                v.x += bs; v.y += bs; v.z += bs; v.w += bs;
                *(float4*)(dst + q * 4) = v;
            }
        }
    }
}

// ------------- deformable conv v8: tap-pipelined, double-buffered samples
// block = 512 threads (8 waves), tile = 128 o x 64 pos, grid = 64 x 8.
// Per tap: interp(t) | write sS[t&1] | ONE barrier | load weights(t) -> regs |
// issue gathers(t+1) | prefetch offsets(t+2) | MFMA(t).
// vmcnt ordering (weights before gathers) keeps t+1 gathers in flight
// through MFMA(t) + loop-around. All pipeline state in NAMED registers.
#define DC_GATHER(T, DY, DX) do {                                              \
    float fy = (float)(h + (T) / KS - PAD) + (DY);                             \
    float fx = (float)(w + (T) % KS - PAD) + (DX);                             \
    float y0f = floorf(fy), x0f = floorf(fx);                                  \
    float wyv = fy - y0f, wxv = fx - x0f;                                      \
    int y0 = (int)y0f, x0 = (int)x0f;                                          \
    w00 = (1.f - wyv) * (1.f - wxv); w01 = (1.f - wyv) * wxv;                  \
    w10 = wyv * (1.f - wxv);         w11 = wyv * wxv;                          \
    bool yv0 = (unsigned)y0 < 64u, yv1 = (unsigned)(y0 + 1) < 64u;             \
    bool xv0 = (unsigned)x0 < 64u, xv1 = (unsigned)(x0 + 1) < 64u;             \
    long bidx = (long)(y0 * 64 + x0) * 128 + cseg;                             \
    cn0 = z4; cn1 = z4; cn2 = z4; cn3 = z4;                                    \
    cn4 = z4; cn5 = z4; cn6 = z4; cn7 = z4;                                    \
    if (yv0 && xv0) { const uint4* p_ = (const uint4*)(ib + bidx);             \
        cn0 = p_[0]; cn1 = p_[1]; }                                            \
    if (yv0 && xv1) { const uint4* p_ = (const uint4*)(ib + bidx + 128);       \
        cn2 = p_[0]; cn3 = p_[1]; }                                            \
    if (yv1 && xv0) { const uint4* p_ = (const uint4*)(ib + bidx + 8192);      \
        cn4 = p_[0]; cn5 = p_[1]; }                                            \
    if (yv1 && xv1) { const uint4* p_ = (const uint4*)(ib + bidx + 8320);      \
        cn6 = p_[0]; cn7 = p_[1]; }                                            \
} while (0)

#define DC_BLEND(RA, RB, RC, RD, OUT) do {                                     \
    unsigned a_[4] = {RA.x, RA.y, RA.z, RA.w};                                 \
    unsigned b_[4] = {RB.x, RB.y, RB.z, RB.w};                                 \
    unsigned c_[4] = {RC.x, RC.y, RC.z, RC.w};                                 \
    unsigned d_[4] = {RD.x, RD.y, RD.z, RD.w};                                 \
    unsigned r_[4];                                                            \
    _Pragma("unroll")                                                          \
    for (int e_ = 0; e_ < 4; ++e_) {                                           \
        float lo_ = w00 * lou(a_[e_]) + w01 * lou(b_[e_])                      \
                  + w10 * lou(c_[e_]) + w11 * lou(d_[e_]);                     \
        float hi_ = w00 * hiu(a_[e_]) + w01 * hiu(b_[e_])                      \
                  + w10 * hiu(c_[e_]) + w11 * hiu(d_[e_]);                     \
        r_[e_] = pk2(lo_, hi_);                                                \
    }                                                                          \
    OUT.x = r_[0]; OUT.y = r_[1]; OUT.z = r_[2]; OUT.w = r_[3];                \
} while (0)

template<int KS>
__global__ __launch_bounds__(512, 4) void k_deform8(
        const unsigned short* __restrict__ img,   // [B][4096][128] bf16
        const float* __restrict__ Off,            // [B][2TT][4096] f32
        const unsigned short* __restrict__ wdT,   // [TT][128][128] bf16 (t,o,c)
        const float* __restrict__ bias,
        unsigned short* __restrict__ catb, int dOff) {
    constexpr int PAD = KS / 2;
    constexpr int TT = KS * KS;
    __shared__ unsigned short sS[2][64][136];  // samples [buf][pos][c], +8 pad
    const int tid = threadIdx.x;
    const int b = blockIdx.z;
    const int p0 = blockIdx.x * 64;            // one h-row per block
    const int wave = tid >> 6, lane = tid & 63, quad = lane >> 4, lr = lane & 15;
    const int m0w = (wave & 3) * 32;           // 4 m-waves x 32 o
    const int n0w = (wave >> 2) * 32;          // 2 n-waves x 32 pos
    const int pos = tid >> 3;                  // 0..63
    const int cseg = (tid & 7) * 16;           // 16-ch segment
    const int pglob = p0 + pos;
    const int h = blockIdx.x, w = pos;
    const unsigned short* ib = img + (size_t)b * HW * 128;
    const float* offb = Off + (size_t)b * 2 * TT * HW;
    const uint4 z4 = make_uint4(0u, 0u, 0u, 0u);

    floatx4 acc00 = {}, acc01 = {}, acc10 = {}, acc11 = {};
    uint4 cn0, cn1, cn2, cn3, cn4, cn5, cn6, cn7;   // corners (A,B,C,D)x2
    float w00, w01, w10, w11;
    float noy = 0.f, nox = 0.f;

    // prologue: gather tap 0; prefetch offsets for tap 1
    {
        float dy0 = offb[pglob];
        float dx0 = offb[HW + pglob];
        DC_GATHER(0, dy0, dx0);
    }
    if (TT > 1) { noy = offb[2 * HW + pglob]; nox = offb[3 * HW + pglob]; }

    for (int t = 0; t < TT; ++t) {
        const int cur = t & 1;
        // INTERP(t): blend corners -> 16 bf16 samples
        uint4 ov0, ov1;
        DC_BLEND(cn0, cn2, cn4, cn6, ov0);
        DC_BLEND(cn1, cn3, cn5, cn7, ov1);
        *(uint4*)&sS[cur][pos][cseg] = ov0;
        *(uint4*)&sS[cur][pos][cseg + 8] = ov1;
        __syncthreads();
        // weights(t) -> named regs (issued BEFORE gathers: MFMA's weight-wait
        // leaves the gathers outstanding)
        const unsigned short* wb = wdT + (size_t)t * 16384
                                   + (size_t)(m0w + lr) * 128 + quad * 8;
        short8 wr0 = *(const short8*)(wb);
        short8 wr1 = *(const short8*)(wb + 2048);        // row +16
        short8 wr2 = *(const short8*)(wb + 32);          // ks=1
        short8 wr3 = *(const short8*)(wb + 2080);
        short8 wr4 = *(const short8*)(wb + 64);          // ks=2
        short8 wr5 = *(const short8*)(wb + 2112);
        short8 wr6 = *(const short8*)(wb + 96);          // ks=3
        short8 wr7 = *(const short8*)(wb + 2144);
        // issue gathers(t+1), prefetch offsets(t+2)
        if (t + 1 < TT) {
            DC_GATHER(t + 1, noy, nox);
            if (t + 2 < TT) {
                noy = offb[(size_t)(2 * t + 4) * HW + pglob];
                nox = offb[(size_t)(2 * t + 5) * HW + pglob];
            }
        }
        // MFMA(t)
        #pragma unroll
        for (int ks = 0; ks < 4; ++ks) {
            short8 bf0 = *(short8*)&sS[cur][n0w + lr][ks * 32 + quad * 8];
            short8 bf1 = *(short8*)&sS[cur][n0w + 16 + lr][ks * 32 + quad * 8];
            short8 a0 = (ks == 0) ? wr0 : (ks == 1) ? wr2 : (ks == 2) ? wr4 : wr6;
            short8 a1 = (ks == 0) ? wr1 : (ks == 1) ? wr3 : (ks == 2) ? wr5 : wr7;
            acc00 = __builtin_amdgcn_mfma_f32_16x16x32_bf16(a0, bf0, acc00, 0, 0, 0);
            acc01 = __builtin_amdgcn_mfma_f32_16x16x32_bf16(a0, bf1, acc01, 0, 0, 0);
            acc10 = __builtin_amdgcn_mfma_f32_16x16x32_bf16(a1, bf0, acc10, 0, 0, 0);
            acc11 = __builtin_amdgcn_mfma_f32_16x16x32_bf16(a1, bf1, acc11, 0, 0, 0);
        }
    }
    // epilogue: bias + bf16 pack via sS[0], coalesced store to catb
    __syncthreads();
    {
        float4 bs = *(const float4*)&bias[m0w + quad * 4];
        float4 bs2 = *(const float4*)&bias[m0w + 16 + quad * 4];
        floatx4 v;
        uint2 st;
        int ch0 = m0w + quad * 4, ch1 = m0w + 16 + quad * 4;
        v = acc00;
        st.x = pk2(v[0] + bs.x, v[1] + bs.y);
        st.y = pk2(v[2] + bs.z, v[3] + bs.w);
        *(uint2*)&sS[0][n0w + lr][ch0] = st;
        v = acc01;
        st.x = pk2(v[0] + bs.x, v[1] + bs.y);
        st.y = pk2(v[2] + bs.z, v[3] + bs.w);
        *(uint2*)&sS[0][n0w + 16 + lr][ch0] = st;
        v = acc10;
        st.x = pk2(v[0] + bs2.x, v[1] + bs2.y);
        st.y = pk2(v[2] + bs2.z, v[3] + bs2.w);
        *(uint2*)&sS[0][n0w + lr][ch1] = st;
        v = acc11;
        st.x = pk2(v[0] + bs2.x, v[1] + bs2.y);
        st.y = pk2(v[2] + bs2.z, v[3] + bs2.w);
        *(uint2*)&sS[0][n0w + 16 + lr][ch1] = st;
    }
    __syncthreads();
    #pragma unroll
    for (int r = 0; r < 2; ++r) {
        int idx = r * 512 + tid;
        int p = idx >> 4, sg = (idx & 15) * 8;
        *(uint4*)&catb[((size_t)b * HW + p0 + p) * 512 + dOff + sg] =
            *(uint4*)&sS[0][p][sg];
    }
}

// ------------------- final: sigmoid(Wcc @ (catb*xbT)) + x, fp32 NCHW output
__global__ __launch_bounds__(256) void k_gemm_final(
        const unsigned short* __restrict__ A, const float* __restrict__ bias,
        const unsigned short* __restrict__ catb, const unsigned short* __restrict__ xbT,
        const float* __restrict__ X, float* __restrict__ OutF) {
    __shared__ unsigned short sA[128][40];
    __shared__ unsigned short sB[128][40];
    const int tid = threadIdx.x;
    const int n0 = blockIdx.x * 128;
    const int o0 = blockIdx.y * 128;
    const int b = blockIdx.z;
    const int wave = tid >> 6, lane = tid & 63, quad = lane >> 4, lr = lane & 15;
    const int m0w = (wave & 1) * 64, n0w = (wave >> 1) * 64;
    const int srow = tid >> 1, skh = (tid & 1) * 16;
    floatx4 acc[4][4] = {};

    for (int k0 = 0; k0 < 512; k0 += 32) {
        const unsigned short* ga = A + (size_t)(o0 + srow) * 512 + k0 + skh;
        uint4 a0 = *(const uint4*)(ga);
        uint4 a1 = *(const uint4*)(ga + 8);
        size_t bi = ((size_t)b * HW + n0 + srow) * 512 + k0 + skh;
        uint4 c0 = *(const uint4*)(catb + bi);
        uint4 c1 = *(const uint4*)(catb + bi + 8);
        uint4 x0 = *(const uint4*)(xbT + bi);
        uint4 x1 = *(const uint4*)(xbT + bi + 8);
        unsigned cu[8] = {c0.x, c0.y, c0.z, c0.w, c1.x, c1.y, c1.z, c1.w};
        unsigned xu[8] = {x0.x, x0.y, x0.z, x0.w, x1.x, x1.y, x1.z, x1.w};
        unsigned mu[8];
        #pragma unroll
        for (int e = 0; e < 8; ++e)
            mu[e] = pk2(lou(cu[e]) * lou(xu[e]), hiu(cu[e]) * hiu(xu[e]));
        __syncthreads();
        *(uint4*)&sA[srow][skh] = a0;
        *(uint4*)&sA[srow][skh + 8] = a1;
        uint4 m0v; m0v.x = mu[0]; m0v.y = mu[1]; m0v.z = mu[2]; m0v.w = mu[3];
        uint4 m1v; m1v.x = mu[4]; m1v.y = mu[5]; m1v.z = mu[6]; m1v.w = mu[7];
        *(uint4*)&sB[srow][skh] = m0v;
        *(uint4*)&sB[srow][skh + 8] = m1v;
        __syncthreads();
        short8 af[4], bf[4];
        #pragma unroll
        for (int i = 0; i < 4; ++i) af[i] = *(short8*)&sA[m0w + i * 16 + lr][quad * 8];
        #pragma unroll
        for (int j = 0; j < 4; ++j) bf[j] = *(short8*)&sB[n0w + j * 16 + lr][quad * 8];
        #pragma unroll
        for (int i = 0; i < 4; ++i)
            #pragma unroll
            for (int j = 0; j < 4; ++j)
                acc[i][j] = __builtin_amdgcn_mfma_f32_16x16x32_bf16(af[i], bf[j], acc[i][j], 0, 0, 0);
    }
    #pragma unroll
    for (int i = 0; i < 4; ++i) {
        float4 bs = *(const float4*)&bias[o0 + m0w + i * 16 + quad * 4];
        float bsa[4] = {bs.x, bs.y, bs.z, bs.w};
        #pragma unroll
        for (int j = 0; j < 4; ++j) {
            floatx4 v = acc[i][j];
            int pos = n0 + n0w + j * 16 + lr;
            #pragma unroll
            for (int rg = 0; rg < 4; ++rg) {
                int o = o0 + m0w + i * 16 + quad * 4 + rg;
                float f = v[rg] + bsa[rg];
                float sg = 1.f / (1.f + __expf(-f));
                size_t idx = ((size_t)b * 512 + o) * HW + pos;
                OutF[idx] = X[idx] + sg;
            }
        }
    }
}

// ------------------------------------------------------------------- launcher
extern "C" void kernel_launch(void* const* d_in, const int* in_sizes, int n_in,
                              void* d_out, int out_size, void* d_ws, size_t ws_size,
                              hipStream_t stream) {
    const float* x      = (const float*)d_in[0];
    const float* w_b1   = (const float*)d_in[1];
    const float* b_b1   = (const float*)d_in[2];
    const float* w_b21  = (const float*)d_in[3];
    const float* b_b21  = (const float*)d_in[4];
    const float* w_off2 = (const float*)d_in[5];
    const float* b_off2 = (const float*)d_in[6];
    const float* w_ddc2 = (const float*)d_in[7];
    const float* b_ddc2 = (const float*)d_in[8];
    const float* w_b31  = (const float*)d_in[9];
    const float* b_b31  = (const float*)d_in[10];
    const float* w_off3 = (const float*)d_in[11];
    const float* b_off3 = (const float*)d_in[12];
    const float* w_ddc3 = (const float*)d_in[13];
    const float* b_ddc3 = (const float*)d_in[14];
    const float* w_b4   = (const float*)d_in[15];
    const float* b_b4   = (const float*)d_in[16];
    const float* w_cc   = (const float*)d_in[17];
    const float* b_cc   = (const float*)d_in[18];

    char* wsb = (char*)d_ws;
    unsigned short* ws8  = (unsigned short*)d_ws;
    unsigned short* xbT  = (unsigned short*)(wsb + O_XBT);
    unsigned short* pxb  = (unsigned short*)(wsb + O_PXB);
    unsigned short* catb = (unsigned short*)(wsb + O_CATB);
    unsigned short* wpb  = (unsigned short*)(wsb + O_WPB);
    unsigned short* w4b  = (unsigned short*)(wsb + O_W4B);
    unsigned short* wccb = (unsigned short*)(wsb + O_WCCB);
    unsigned short* wd2t = (unsigned short*)(wsb + O_WD2T);
    unsigned short* wd3t = (unsigned short*)(wsb + O_WD3T);
    unsigned short* wo2t = (unsigned short*)(wsb + O_WO2T);
    unsigned short* wo3t = (unsigned short*)(wsb + O_WO3T);
    unsigned short* t2b  = (unsigned short*)(wsb + O_T2B);
    unsigned short* t3b  = (unsigned short*)(wsb + O_T3B);
    float* off2 = (float*)(wsb + O_OFF2);
    float* off3 = (float*)(wsb + O_OFF3);
    float* out  = (float*)d_out;

    k_prepw<<<dim3(5312), dim3(256), 0, stream>>>(
        w_b1, w_b21, w_b31, w_b4, w_cc, w_ddc2, w_ddc3, w_off2, w_off3, ws8);
    k_xpose<<<dim3(128, 16, 8), dim3(256), 0, stream>>>(x, xbT);
    k_pool<<<dim3(8192), dim3(256), 0, stream>>>(xbT, pxb);
    // b4 first (frees pxb region for t2b/t3b/offsets)
    k_gemm<<<dim3(32, 1, 8), dim3(256), 0, stream>>>(w4b, b_b4, pxb, catb, 512, 384);
    k_gemm<<<dim3(32, 1, 8), dim3(256), 0, stream>>>(wpb, b_b1, xbT, catb, 512, 0);
    k_gemm<<<dim3(32, 1, 8), dim3(256), 0, stream>>>(wpb + 128 * 512, b_b21, xbT, t2b, 128, 0);
    k_gemm<<<dim3(32, 1, 8), dim3(256), 0, stream>>>(wpb + 256 * 512, b_b31, xbT, t3b, 128, 0);
    k_offconv2<3, 18><<<dim3(32, 1, 8), dim3(512), 0, stream>>>(t2b, wo2t, b_off2, off2);
    k_offconv2<5, 50><<<dim3(32, 1, 8), dim3(512), 0, stream>>>(t3b, wo3t, b_off3, off3);
    k_deform8<3><<<dim3(64, 1, 8), dim3(512), 0, stream>>>(t2b, off2, wd2t, b_ddc2, catb, 128);
    k_deform8<5><<<dim3(64, 1, 8), dim3(512), 0, stream>>>(t3b, off3, wd3t, b_ddc3, catb, 256);
    k_gemm_final<<<dim3(32, 4, 8), dim3(256), 0, stream>>>(wccb, b_cc, catb, xbT, x, out);
}

// Round 5
// 548.099 us; speedup vs baseline: 1.4602x; 1.0116x over previous
//
#include <hip/hip_runtime.h>
#include <math.h>

#define HW 4096
typedef short short8 __attribute__((ext_vector_type(8)));
typedef float floatx4 __attribute__((ext_vector_type(4)));

// ---- ws layout (bytes) ----
#define O_XBT   0ull            // [8][4096][512] bf16 x NHWC
#define O_PXB   33554432ull     // [8][4096][512] bf16 pooled x NHWC (reused later)
#define O_CATB  67108864ull     // [8][4096][512] bf16 cat branches NHWC
#define O_WPB   100663296ull    // [384][512] bf16
#define O_W4B   101056512ull    // [128][512] bf16
#define O_WCCB  101187584ull    // [512][512] bf16
#define O_WD2T  101711872ull    // [9][128][128] bf16 (t,o,c)
#define O_WD3T  102006784ull    // [25][128][128] bf16 (t,o,c)
#define O_WO2T  102825984ull    // [9][64][128] bf16 (t,o,c)
#define O_WO3T  102973440ull    // [25][64][128] bf16 (t,o,c)
// reuse of PXB region after b4 GEMM:
#define O_T2B   33554432ull     // [8][4096][128] bf16 b2i NHWC
#define O_T3B   41943040ull     // [8][4096][128] bf16 b3i NHWC
#define O_OFF2  50331648ull     // [8][18][4096] f32
#define O_OFF3  52690944ull     // [8][50][4096] f32

__device__ __forceinline__ unsigned short f2b(float f) {
    union { float f; unsigned u; } v; v.f = f;
    unsigned r = v.u + 0x7FFFu + ((v.u >> 16) & 1u);
    return (unsigned short)(r >> 16);
}
__device__ __forceinline__ float lou(unsigned u) {
    union { unsigned u; float f; } v; v.u = u << 16; return v.f;
}
__device__ __forceinline__ float hiu(unsigned u) {
    union { unsigned u; float f; } v; v.u = u & 0xFFFF0000u; return v.f;
}
__device__ __forceinline__ unsigned pk2(float lo, float hi) {
    return (unsigned)f2b(lo) | ((unsigned)f2b(hi) << 16);
}

// ------------------------------------------------------------- weight prep
__global__ __launch_bounds__(256) void k_prepw(
        const float* __restrict__ w1, const float* __restrict__ w21,
        const float* __restrict__ w31, const float* __restrict__ w4,
        const float* __restrict__ wcc, const float* __restrict__ wd2,
        const float* __restrict__ wd3, const float* __restrict__ wo2,
        const float* __restrict__ wo3, unsigned short* __restrict__ ws8) {
    unsigned i = blockIdx.x * 256 + threadIdx.x;
    unsigned short* wpb  = ws8 + (O_WPB  >> 1);
    unsigned short* w4b  = ws8 + (O_W4B  >> 1);
    unsigned short* wccb = ws8 + (O_WCCB >> 1);
    unsigned short* wd2t = ws8 + (O_WD2T >> 1);
    unsigned short* wd3t = ws8 + (O_WD3T >> 1);
    unsigned short* wo2t = ws8 + (O_WO2T >> 1);
    unsigned short* wo3t = ws8 + (O_WO3T >> 1);
    if (i < 196608) {
        int o = i >> 9;
        float v = (o < 128) ? w1[i] : (o < 256) ? w21[i - 65536] : w31[i - 131072];
        wpb[i] = f2b(v);
    } else if (i < 262144) {
        unsigned j = i - 196608; w4b[j] = f2b(w4[j]);
    } else if (i < 524288) {
        unsigned j = i - 262144; wccb[j] = f2b(wcc[j]);
    } else if (i < 671744) {
        unsigned j = i - 524288; int t = j >> 14, o = (j >> 7) & 127, c = j & 127;
        wd2t[j] = f2b(wd2[((o * 128 + c) * 9) + t]);
    } else if (i < 1081344) {
        unsigned j = i - 671744; int t = j >> 14, o = (j >> 7) & 127, c = j & 127;
        wd3t[j] = f2b(wd3[((o * 128 + c) * 25) + t]);
    } else if (i < 1155072) {
        // layout (t, o, c): j = (t*64 + o)*128 + c
        unsigned j = i - 1081344; int t = j >> 13, o = (j >> 7) & 63, c = j & 127;
        wo2t[j] = (o < 18) ? f2b(wo2[((o * 128 + c) * 9) + t]) : 0;
    } else if (i < 1359872) {
        unsigned j = i - 1155072; int t = j >> 13, o = (j >> 7) & 63, c = j & 127;
        wo3t[j] = (o < 50) ? f2b(wo3[((o * 128 + c) * 25) + t]) : 0;
    }
}

// ---------------------------------------- x NCHW f32 -> NHWC bf16 transpose
__global__ __launch_bounds__(256) void k_xpose(const float* __restrict__ X,
                                               unsigned short* __restrict__ xbT) {
    __shared__ unsigned short t[32][33];
    const int p0 = blockIdx.x * 32, c0 = blockIdx.y * 32, b = blockIdx.z;
    const int tid = threadIdx.x;
    #pragma unroll
    for (int s = 0; s < 4; ++s) {
        int cl = s * 8 + (tid >> 5), pl = tid & 31;
        t[cl][pl] = f2b(X[((size_t)b * 512 + c0 + cl) * HW + p0 + pl]);
    }
    __syncthreads();
    #pragma unroll
    for (int s = 0; s < 4; ++s) {
        int pl = s * 8 + (tid >> 5), cl = tid & 31;
        xbT[((size_t)b * HW + p0 + pl) * 512 + c0 + cl] = t[cl][pl];
    }
}

// ----------------------------------------------- 3x3 s1 maxpool on NHWC bf16
__global__ __launch_bounds__(256) void k_pool(const unsigned short* __restrict__ xbT,
                                              unsigned short* __restrict__ pxb) {
    unsigned gid = blockIdx.x * 256 + threadIdx.x;   // 8*4096*64
    int b = gid >> 18;
    unsigned rem = gid & 262143;
    int pos = rem >> 6;
    int cg = (rem & 63) * 8;
    int h = pos >> 6, w = pos & 63;
    const unsigned short* img = xbT + (size_t)b * HW * 512;
    float m[8] = {-INFINITY, -INFINITY, -INFINITY, -INFINITY,
                  -INFINITY, -INFINITY, -INFINITY, -INFINITY};
    #pragma unroll
    for (int dy = -1; dy <= 1; ++dy) {
        int hh = h + dy;
        if (hh < 0 || hh >= 64) continue;
        #pragma unroll
        for (int dx = -1; dx <= 1; ++dx) {
            int ww = w + dx;
            if (ww < 0 || ww >= 64) continue;
            uint4 v = *(const uint4*)(img + ((size_t)(hh * 64 + ww)) * 512 + cg);
            unsigned uu[4] = {v.x, v.y, v.z, v.w};
            #pragma unroll
            for (int e = 0; e < 4; ++e) {
                m[2 * e]     = fmaxf(m[2 * e],     lou(uu[e]));
                m[2 * e + 1] = fmaxf(m[2 * e + 1], hiu(uu[e]));
            }
        }
    }
    uint4 o;
    o.x = pk2(m[0], m[1]); o.y = pk2(m[2], m[3]);
    o.z = pk2(m[4], m[5]); o.w = pk2(m[6], m[7]);
    *(uint4*)(pxb + ((size_t)b * HW + pos) * 512 + cg) = o;
}

// ----------------------------- bf16 MFMA GEMM: C[128 x 128pos] = A[128x512]B
#define SA(r,c) SM[(r)*40 + (c)]
#define SB(r,c) SM[5120 + (r)*40 + (c)]
#define SC(r,c) SM[(r)*136 + (c)]
__global__ __launch_bounds__(256) void k_gemm(
        const unsigned short* __restrict__ A, const float* __restrict__ bias,
        const unsigned short* __restrict__ Bm,
        unsigned short* __restrict__ dst, int dStride, int dOff) {
    __shared__ unsigned short SM[17408];
    const int tid = threadIdx.x;
    const int n0 = blockIdx.x * 128;
    const int b = blockIdx.z;
    const int wave = tid >> 6, lane = tid & 63, quad = lane >> 4, lr = lane & 15;
    const int m0w = (wave & 1) * 64, n0w = (wave >> 1) * 64;
    const int srow = tid >> 1, skh = (tid & 1) * 16;
    floatx4 acc[4][4] = {};

    for (int k0 = 0; k0 < 512; k0 += 32) {
        const unsigned short* ga = A + (size_t)srow * 512 + k0 + skh;
        uint4 a0 = *(const uint4*)(ga);
        uint4 a1 = *(const uint4*)(ga + 8);
        const unsigned short* gb = Bm + ((size_t)b * HW + n0 + srow) * 512 + k0 + skh;
        uint4 b0 = *(const uint4*)(gb);
        uint4 b1 = *(const uint4*)(gb + 8);
        __syncthreads();
        *(uint4*)&SA(srow, skh) = a0;
        *(uint4*)&SA(srow, skh + 8) = a1;
        *(uint4*)&SB(srow, skh) = b0;
        *(uint4*)&SB(srow, skh + 8) = b1;
        __syncthreads();
        short8 af[4], bf[4];
        #pragma unroll
        for (int i = 0; i < 4; ++i) af[i] = *(short8*)&SA(m0w + i * 16 + lr, quad * 8);
        #pragma unroll
        for (int j = 0; j < 4; ++j) bf[j] = *(short8*)&SB(n0w + j * 16 + lr, quad * 8);
        #pragma unroll
        for (int i = 0; i < 4; ++i)
            #pragma unroll
            for (int j = 0; j < 4; ++j)
                acc[i][j] = __builtin_amdgcn_mfma_f32_16x16x32_bf16(af[i], bf[j], acc[i][j], 0, 0, 0);
    }
    __syncthreads();
    #pragma unroll
    for (int i = 0; i < 4; ++i) {
        float4 bs = *(const float4*)&bias[m0w + i * 16 + quad * 4];
        #pragma unroll
        for (int j = 0; j < 4; ++j) {
            floatx4 v = acc[i][j];
            int pos = n0w + j * 16 + lr;
            int ch = m0w + i * 16 + quad * 4;
            uint2 st;
            st.x = pk2(v[0] + bs.x, v[1] + bs.y);
            st.y = pk2(v[2] + bs.z, v[3] + bs.w);
            *(uint2*)&SC(pos, ch) = st;
        }
    }
    __syncthreads();
    #pragma unroll
    for (int r = 0; r < 8; ++r) {
        int pos = (tid >> 4) + r * 16;
        *(uint4*)&dst[((size_t)b * HW + n0 + pos) * dStride + dOff + (tid & 15) * 8] =
            *(uint4*)&SC(pos, (tid & 15) * 8);
    }
}

// ---------------- offset convs v2: slab-staged, barrier-free tap loop
// block = 128 positions (2 h-rows) x 64 M (padded), 512 threads.
template<int KS, int OCH>
__global__ __launch_bounds__(512) void k_offconv2(
        const unsigned short* __restrict__ img,   // [B][4096][128] bf16
        const unsigned short* __restrict__ woT,   // [TT][64][128] bf16 (t,o,c)
        const float* __restrict__ bias, float* __restrict__ Out) {
    constexpr int PAD = KS / 2;
    constexpr int TT = KS * KS;
    constexpr int SR = 2 + 2 * PAD;
    constexpr int SC2 = 64 + 2 * PAD;
    constexpr int NE = SR * SC2;              // slab entries
    __shared__ unsigned short slab[NE * 36];  // [entry][36] (32 ch + pad)
    __shared__ float ctile[64 * 132];
    const int tid = threadIdx.x;
    const int p0 = blockIdx.x * 128, hrow0 = blockIdx.x * 2, b = blockIdx.z;
    const int wave = tid >> 6, lane = tid & 63, quad = lane >> 4, lr = lane & 15;
    const int wm = wave & 1, wn = wave >> 1;   // 2 x 4 wave grid: 32o x 32pos
    const unsigned short* ib = img + (size_t)b * HW * 128;
    floatx4 acc[2][2] = {};

    for (int c0 = 0; c0 < 128; c0 += 32) {
        __syncthreads();
        if (tid < NE) {
            int s = tid / SC2, cl = tid % SC2;
            int r = hrow0 - PAD + s, cc = cl - PAD;
            uint4 v0 = {}, v1 = {}, v2 = {}, v3 = {};
            if ((unsigned)r < 64u && (unsigned)cc < 64u) {
                const uint4* g = (const uint4*)(ib + ((size_t)(r * 64 + cc)) * 128 + c0);
                v0 = g[0]; v1 = g[1]; v2 = g[2]; v3 = g[3];
            }
            uint2* d2 = (uint2*)&slab[tid * 36];
            d2[0] = make_uint2(v0.x, v0.y); d2[1] = make_uint2(v0.z, v0.w);
            d2[2] = make_uint2(v1.x, v1.y); d2[3] = make_uint2(v1.z, v1.w);
            d2[4] = make_uint2(v2.x, v2.y); d2[5] = make_uint2(v2.z, v2.w);
            d2[6] = make_uint2(v3.x, v3.y); d2[7] = make_uint2(v3.z, v3.w);
        }
        __syncthreads();
        #pragma unroll
        for (int t = 0; t < TT; ++t) {
            const int ky = t / KS, kx = t % KS;
            short8 af[2], bf[2];
            #pragma unroll
            for (int i = 0; i < 2; ++i)
                af[i] = *(const short8*)&woT[((size_t)t * 64 + wm * 32 + i * 16 + lr) * 128
                                             + c0 + quad * 8];
            #pragma unroll
            for (int j = 0; j < 2; ++j) {
                int p = wn * 32 + j * 16 + lr;
                int e = ((p >> 6) + ky) * SC2 + (p & 63) + kx;
                union { uint2 u[2]; short8 s; } bb;
                const uint2* sp = (const uint2*)&slab[e * 36 + quad * 8];
                bb.u[0] = sp[0]; bb.u[1] = sp[1];
                bf[j] = bb.s;
            }
            #pragma unroll
            for (int i = 0; i < 2; ++i)
                #pragma unroll
                for (int j = 0; j < 2; ++j)
                    acc[i][j] = __builtin_amdgcn_mfma_f32_16x16x32_bf16(af[i], bf[j], acc[i][j], 0, 0, 0);
        }
    }
    __syncthreads();
    #pragma unroll
    for (int i = 0; i < 2; ++i)
        #pragma unroll
        for (int j = 0; j < 2; ++j) {
            floatx4 v = acc[i][j];
            int p = wn * 32 + j * 16 + lr;
            int o = wm * 32 + i * 16 + quad * 4;
            #pragma unroll
            for (int rg = 0; rg < 4; ++rg)
                ctile[(o + rg) * 132 + p] = v[rg];
        }
    __syncthreads();
    {
        int o = tid >> 3, seg = tid & 7;
        if (o < OCH) {
            float bs = bias[o];
            const float* src = &ctile[o * 132 + seg * 16];
            float* dst = &Out[((size_t)b * OCH + o) * HW + p0 + seg * 16];
            #pragma unroll
            for (int q = 0; q < 4; ++q) {
                float4 v = *(const float4*)(src + q * 4);
                v.x += bs; v.y += bs; v.z += bs; v.w += bs;
                *(float4*)(dst + q * 4) = v;
            }
        }
    }
}

// ------------- deformable conv v9: XCD-pinned batch + cvt_pk blend
// grid (64,1,8); in-kernel remap: batch = blockIdx.x & 7 (== XCD under the
// L%8 round-robin model), tile = (blockIdx.x>>3) + 8*blockIdx.z.
// -> per-XCD L2 working set = 1 image (1MB) + offsets + weights < 4MB
// -> gather HBM misses (the per-tap straggler latency) vanish.
#define DC_GATHER(T, DY, DX) do {                                              \
    float fy = (float)(h + (T) / KS - PAD) + (DY);                             \
    float fx = (float)(w + (T) % KS - PAD) + (DX);                             \
    float y0f = floorf(fy), x0f = floorf(fx);                                  \
    float wyv = fy - y0f, wxv = fx - x0f;                                      \
    int y0 = (int)y0f, x0 = (int)x0f;                                          \
    w00 = (1.f - wyv) * (1.f - wxv); w01 = (1.f - wyv) * wxv;                  \
    w10 = wyv * (1.f - wxv);         w11 = wyv * wxv;                          \
    bool yv0 = (unsigned)y0 < 64u, yv1 = (unsigned)(y0 + 1) < 64u;             \
    bool xv0 = (unsigned)x0 < 64u, xv1 = (unsigned)(x0 + 1) < 64u;             \
    long bidx = (long)(y0 * 64 + x0) * 128 + cseg;                             \
    cn0 = z4; cn1 = z4; cn2 = z4; cn3 = z4;                                    \
    cn4 = z4; cn5 = z4; cn6 = z4; cn7 = z4;                                    \
    if (yv0 && xv0) { const uint4* p_ = (const uint4*)(ib + bidx);             \
        cn0 = p_[0]; cn1 = p_[1]; }                                            \
    if (yv0 && xv1) { const uint4* p_ = (const uint4*)(ib + bidx + 128);       \
        cn2 = p_[0]; cn3 = p_[1]; }                                            \
    if (yv1 && xv0) { const uint4* p_ = (const uint4*)(ib + bidx + 8192);      \
        cn4 = p_[0]; cn5 = p_[1]; }                                            \
    if (yv1 && xv1) { const uint4* p_ = (const uint4*)(ib + bidx + 8320);      \
        cn6 = p_[0]; cn7 = p_[1]; }                                            \
} while (0)

// blend with v_cvt_pk_bf16_f32 (RNE, bit-identical to f2b emulation)
#define DC_BLEND(RA, RB, RC, RD, OUT) do {                                     \
    unsigned a_[4] = {RA.x, RA.y, RA.z, RA.w};                                 \
    unsigned b_[4] = {RB.x, RB.y, RB.z, RB.w};                                 \
    unsigned c_[4] = {RC.x, RC.y, RC.z, RC.w};                                 \
    unsigned d_[4] = {RD.x, RD.y, RD.z, RD.w};                                 \
    unsigned r_[4];                                                            \
    _Pragma("unroll")                                                          \
    for (int e_ = 0; e_ < 4; ++e_) {                                           \
        float lo_ = w00 * lou(a_[e_]) + w01 * lou(b_[e_])                      \
                  + w10 * lou(c_[e_]) + w11 * lou(d_[e_]);                     \
        float hi_ = w00 * hiu(a_[e_]) + w01 * hiu(b_[e_])                      \
                  + w10 * hiu(c_[e_]) + w11 * hiu(d_[e_]);                     \
        asm("v_cvt_pk_bf16_f32 %0, %1, %2"                                     \
            : "=v"(r_[e_]) : "v"(lo_), "v"(hi_));                              \
    }                                                                          \
    OUT.x = r_[0]; OUT.y = r_[1]; OUT.z = r_[2]; OUT.w = r_[3];                \
} while (0)

template<int KS>
__global__ __launch_bounds__(512, 4) void k_deform9(
        const unsigned short* __restrict__ img,   // [B][4096][128] bf16
        const float* __restrict__ Off,            // [B][2TT][4096] f32
        const unsigned short* __restrict__ wdT,   // [TT][128][128] bf16 (t,o,c)
        const float* __restrict__ bias,
        unsigned short* __restrict__ catb, int dOff) {
    constexpr int PAD = KS / 2;
    constexpr int TT = KS * KS;
    __shared__ unsigned short sS[2][64][136];  // samples [buf][pos][c], +8 pad
    const int tid = threadIdx.x;
    // XCD-pinned remap: all blocks of batch b land on XCD b (L%8 model)
    const int b = blockIdx.x & 7;
    const int tile = (blockIdx.x >> 3) + 8 * blockIdx.z;   // 0..63 h-row
    const int p0 = tile * 64;
    const int wave = tid >> 6, lane = tid & 63, quad = lane >> 4, lr = lane & 15;
    const int m0w = (wave & 3) * 32;           // 4 m-waves x 32 o
    const int n0w = (wave >> 2) * 32;          // 2 n-waves x 32 pos
    const int pos = tid >> 3;                  // 0..63
    const int cseg = (tid & 7) * 16;           // 16-ch segment
    const int pglob = p0 + pos;
    const int h = tile, w = pos;
    const unsigned short* ib = img + (size_t)b * HW * 128;
    const float* offb = Off + (size_t)b * 2 * TT * HW;
    const uint4 z4 = make_uint4(0u, 0u, 0u, 0u);

    floatx4 acc00 = {}, acc01 = {}, acc10 = {}, acc11 = {};
    uint4 cn0, cn1, cn2, cn3, cn4, cn5, cn6, cn7;   // corners (A,B,C,D)x2
    float w00, w01, w10, w11;
    float noy = 0.f, nox = 0.f;

    // prologue: gather tap 0; prefetch offsets for tap 1
    {
        float dy0 = offb[pglob];
        float dx0 = offb[HW + pglob];
        DC_GATHER(0, dy0, dx0);
    }
    if (TT > 1) { noy = offb[2 * HW + pglob]; nox = offb[3 * HW + pglob]; }

    for (int t = 0; t < TT; ++t) {
        const int cur = t & 1;
        // INTERP(t): blend corners -> 16 bf16 samples
        uint4 ov0, ov1;
        DC_BLEND(cn0, cn2, cn4, cn6, ov0);
        DC_BLEND(cn1, cn3, cn5, cn7, ov1);
        *(uint4*)&sS[cur][pos][cseg] = ov0;
        *(uint4*)&sS[cur][pos][cseg + 8] = ov1;
        __syncthreads();
        // weights(t) -> named regs (issued BEFORE gathers: MFMA's weight-wait
        // leaves the gathers outstanding)
        const unsigned short* wb = wdT + (size_t)t * 16384
                                   + (size_t)(m0w + lr) * 128 + quad * 8;
        short8 wr0 = *(const short8*)(wb);
        short8 wr1 = *(const short8*)(wb + 2048);        // row +16
        short8 wr2 = *(const short8*)(wb + 32);          // ks=1
        short8 wr3 = *(const short8*)(wb + 2080);
        short8 wr4 = *(const short8*)(wb + 64);          // ks=2
        short8 wr5 = *(const short8*)(wb + 2112);
        short8 wr6 = *(const short8*)(wb + 96);          // ks=3
        short8 wr7 = *(const short8*)(wb + 2144);
        // issue gathers(t+1), prefetch offsets(t+2)
        if (t + 1 < TT) {
            DC_GATHER(t + 1, noy, nox);
            if (t + 2 < TT) {
                noy = offb[(size_t)(2 * t + 4) * HW + pglob];
                nox = offb[(size_t)(2 * t + 5) * HW + pglob];
            }
        }
        // MFMA(t)
        #pragma unroll
        for (int ks = 0; ks < 4; ++ks) {
            short8 bf0 = *(short8*)&sS[cur][n0w + lr][ks * 32 + quad * 8];
            short8 bf1 = *(short8*)&sS[cur][n0w + 16 + lr][ks * 32 + quad * 8];
            short8 a0 = (ks == 0) ? wr0 : (ks == 1) ? wr2 : (ks == 2) ? wr4 : wr6;
            short8 a1 = (ks == 0) ? wr1 : (ks == 1) ? wr3 : (ks == 2) ? wr5 : wr7;
            acc00 = __builtin_amdgcn_mfma_f32_16x16x32_bf16(a0, bf0, acc00, 0, 0, 0);
            acc01 = __builtin_amdgcn_mfma_f32_16x16x32_bf16(a0, bf1, acc01, 0, 0, 0);
            acc10 = __builtin_amdgcn_mfma_f32_16x16x32_bf16(a1, bf0, acc10, 0, 0, 0);
            acc11 = __builtin_amdgcn_mfma_f32_16x16x32_bf16(a1, bf1, acc11, 0, 0, 0);
        }
    }
    // epilogue: bias + bf16 pack via sS[0], coalesced store to catb
    __syncthreads();
    {
        float4 bs = *(const float4*)&bias[m0w + quad * 4];
        float4 bs2 = *(const float4*)&bias[m0w + 16 + quad * 4];
        floatx4 v;
        uint2 st;
        int ch0 = m0w + quad * 4, ch1 = m0w + 16 + quad * 4;
        v = acc00;
        st.x = pk2(v[0] + bs.x, v[1] + bs.y);
        st.y = pk2(v[2] + bs.z, v[3] + bs.w);
        *(uint2*)&sS[0][n0w + lr][ch0] = st;
        v = acc01;
        st.x = pk2(v[0] + bs.x, v[1] + bs.y);
        st.y = pk2(v[2] + bs.z, v[3] + bs.w);
        *(uint2*)&sS[0][n0w + 16 + lr][ch0] = st;
        v = acc10;
        st.x = pk2(v[0] + bs2.x, v[1] + bs2.y);
        st.y = pk2(v[2] + bs2.z, v[3] + bs2.w);
        *(uint2*)&sS[0][n0w + lr][ch1] = st;
        v = acc11;
        st.x = pk2(v[0] + bs2.x, v[1] + bs2.y);
        st.y = pk2(v[2] + bs2.z, v[3] + bs2.w);
        *(uint2*)&sS[0][n0w + 16 + lr][ch1] = st;
    }
    __syncthreads();
    #pragma unroll
    for (int r = 0; r < 2; ++r) {
        int idx = r * 512 + tid;
        int p = idx >> 4, sg = (idx & 15) * 8;
        *(uint4*)&catb[((size_t)b * HW + p0 + p) * 512 + dOff + sg] =
            *(uint4*)&sS[0][p][sg];
    }
}

// ------------------- final: sigmoid(Wcc @ (catb*xbT)) + x, fp32 NCHW output
__global__ __launch_bounds__(256) void k_gemm_final(
        const unsigned short* __restrict__ A, const float* __restrict__ bias,
        const unsigned short* __restrict__ catb, const unsigned short* __restrict__ xbT,
        const float* __restrict__ X, float* __restrict__ OutF) {
    __shared__ unsigned short sA[128][40];
    __shared__ unsigned short sB[128][40];
    const int tid = threadIdx.x;
    const int n0 = blockIdx.x * 128;
    const int o0 = blockIdx.y * 128;
    const int b = blockIdx.z;
    const int wave = tid >> 6, lane = tid & 63, quad = lane >> 4, lr = lane & 15;
    const int m0w = (wave & 1) * 64, n0w = (wave >> 1) * 64;
    const int srow = tid >> 1, skh = (tid & 1) * 16;
    floatx4 acc[4][4] = {};

    for (int k0 = 0; k0 < 512; k0 += 32) {
        const unsigned short* ga = A + (size_t)(o0 + srow) * 512 + k0 + skh;
        uint4 a0 = *(const uint4*)(ga);
        uint4 a1 = *(const uint4*)(ga + 8);
        size_t bi = ((size_t)b * HW + n0 + srow) * 512 + k0 + skh;
        uint4 c0 = *(const uint4*)(catb + bi);
        uint4 c1 = *(const uint4*)(catb + bi + 8);
        uint4 x0 = *(const uint4*)(xbT + bi);
        uint4 x1 = *(const uint4*)(xbT + bi + 8);
        unsigned cu[8] = {c0.x, c0.y, c0.z, c0.w, c1.x, c1.y, c1.z, c1.w};
        unsigned xu[8] = {x0.x, x0.y, x0.z, x0.w, x1.x, x1.y, x1.z, x1.w};
        unsigned mu[8];
        #pragma unroll
        for (int e = 0; e < 8; ++e)
            mu[e] = pk2(lou(cu[e]) * lou(xu[e]), hiu(cu[e]) * hiu(xu[e]));
        __syncthreads();
        *(uint4*)&sA[srow][skh] = a0;
        *(uint4*)&sA[srow][skh + 8] = a1;
        uint4 m0v; m0v.x = mu[0]; m0v.y = mu[1]; m0v.z = mu[2]; m0v.w = mu[3];
        uint4 m1v; m1v.x = mu[4]; m1v.y = mu[5]; m1v.z = mu[6]; m1v.w = mu[7];
        *(uint4*)&sB[srow][skh] = m0v;
        *(uint4*)&sB[srow][skh + 8] = m1v;
        __syncthreads();
        short8 af[4], bf[4];
        #pragma unroll
        for (int i = 0; i < 4; ++i) af[i] = *(short8*)&sA[m0w + i * 16 + lr][quad * 8];
        #pragma unroll
        for (int j = 0; j < 4; ++j) bf[j] = *(short8*)&sB[n0w + j * 16 + lr][quad * 8];
        #pragma unroll
        for (int i = 0; i < 4; ++i)
            #pragma unroll
            for (int j = 0; j < 4; ++j)
                acc[i][j] = __builtin_amdgcn_mfma_f32_16x16x32_bf16(af[i], bf[j], acc[i][j], 0, 0, 0);
    }
    #pragma unroll
    for (int i = 0; i < 4; ++i) {
        float4 bs = *(const float4*)&bias[o0 + m0w + i * 16 + quad * 4];
        float bsa[4] = {bs.x, bs.y, bs.z, bs.w};
        #pragma unroll
        for (int j = 0; j < 4; ++j) {
            floatx4 v = acc[i][j];
            int pos = n0 + n0w + j * 16 + lr;
            #pragma unroll
            for (int rg = 0; rg < 4; ++rg) {
                int o = o0 + m0w + i * 16 + quad * 4 + rg;
                float f = v[rg] + bsa[rg];
                float sg = 1.f / (1.f + __expf(-f));
                size_t idx = ((size_t)b * 512 + o) * HW + pos;
                OutF[idx] = X[idx] + sg;
            }
        }
    }
}

// ------------------------------------------------------------------- launcher
extern "C" void kernel_launch(void* const* d_in, const int* in_sizes, int n_in,
                              void* d_out, int out_size, void* d_ws, size_t ws_size,
                              hipStream_t stream) {
    const float* x      = (const float*)d_in[0];
    const float* w_b1   = (const float*)d_in[1];
    const float* b_b1   = (const float*)d_in[2];
    const float* w_b21  = (const float*)d_in[3];
    const float* b_b21  = (const float*)d_in[4];
    const float* w_off2 = (const float*)d_in[5];
    const float* b_off2 = (const float*)d_in[6];
    const float* w_ddc2 = (const float*)d_in[7];
    const float* b_ddc2 = (const float*)d_in[8];
    const float* w_b31  = (const float*)d_in[9];
    const float* b_b31  = (const float*)d_in[10];
    const float* w_off3 = (const float*)d_in[11];
    const float* b_off3 = (const float*)d_in[12];
    const float* w_ddc3 = (const float*)d_in[13];
    const float* b_ddc3 = (const float*)d_in[14];
    const float* w_b4   = (const float*)d_in[15];
    const float* b_b4   = (const float*)d_in[16];
    const float* w_cc   = (const float*)d_in[17];
    const float* b_cc   = (const float*)d_in[18];

    char* wsb = (char*)d_ws;
    unsigned short* ws8  = (unsigned short*)d_ws;
    unsigned short* xbT  = (unsigned short*)(wsb + O_XBT);
    unsigned short* pxb  = (unsigned short*)(wsb + O_PXB);
    unsigned short* catb = (unsigned short*)(wsb + O_CATB);
    unsigned short* wpb  = (unsigned short*)(wsb + O_WPB);
    unsigned short* w4b  = (unsigned short*)(wsb + O_W4B);
    unsigned short* wccb = (unsigned short*)(wsb + O_WCCB);
    unsigned short* wd2t = (unsigned short*)(wsb + O_WD2T);
    unsigned short* wd3t = (unsigned short*)(wsb + O_WD3T);
    unsigned short* wo2t = (unsigned short*)(wsb + O_WO2T);
    unsigned short* wo3t = (unsigned short*)(wsb + O_WO3T);
    unsigned short* t2b  = (unsigned short*)(wsb + O_T2B);
    unsigned short* t3b  = (unsigned short*)(wsb + O_T3B);
    float* off2 = (float*)(wsb + O_OFF2);
    float* off3 = (float*)(wsb + O_OFF3);
    float* out  = (float*)d_out;

    k_prepw<<<dim3(5312), dim3(256), 0, stream>>>(
        w_b1, w_b21, w_b31, w_b4, w_cc, w_ddc2, w_ddc3, w_off2, w_off3, ws8);
    k_xpose<<<dim3(128, 16, 8), dim3(256), 0, stream>>>(x, xbT);
    k_pool<<<dim3(8192), dim3(256), 0, stream>>>(xbT, pxb);
    // b4 first (frees pxb region for t2b/t3b/offsets)
    k_gemm<<<dim3(32, 1, 8), dim3(256), 0, stream>>>(w4b, b_b4, pxb, catb, 512, 384);
    k_gemm<<<dim3(32, 1, 8), dim3(256), 0, stream>>>(wpb, b_b1, xbT, catb, 512, 0);
    k_gemm<<<dim3(32, 1, 8), dim3(256), 0, stream>>>(wpb + 128 * 512, b_b21, xbT, t2b, 128, 0);
    k_gemm<<<dim3(32, 1, 8), dim3(256), 0, stream>>>(wpb + 256 * 512, b_b31, xbT, t3b, 128, 0);
    k_offconv2<3, 18><<<dim3(32, 1, 8), dim3(512), 0, stream>>>(t2b, wo2t, b_off2, off2);
    k_offconv2<5, 50><<<dim3(32, 1, 8), dim3(512), 0, stream>>>(t3b, wo3t, b_off3, off3);
    k_deform9<3><<<dim3(64, 1, 8), dim3(512), 0, stream>>>(t2b, off2, wd2t, b_ddc2, catb, 128);
    k_deform9<5><<<dim3(64, 1, 8), dim3(512), 0, stream>>>(t3b, off3, wd3t, b_ddc3, catb, 256);
    k_gemm_final<<<dim3(32, 4, 8), dim3(256), 0, stream>>>(wccb, b_cc, catb, xbT, x, out);
}

// Round 6
// 545.724 us; speedup vs baseline: 1.4666x; 1.0044x over previous
//
#include <hip/hip_runtime.h>
#include <math.h>

#define HW 4096
typedef short short8 __attribute__((ext_vector_type(8)));
typedef float floatx4 __attribute__((ext_vector_type(4)));

// ---- ws layout (bytes) ----
#define O_XBT   0ull            // [8][4096][512] bf16 x NHWC
#define O_PXB   33554432ull     // [8][4096][512] bf16 pooled x NHWC (reused later)
#define O_CATB  67108864ull     // [8][4096][512] bf16 cat branches NHWC
#define O_WPB   100663296ull    // [384][512] bf16
#define O_W4B   101056512ull    // [128][512] bf16
#define O_WCCB  101187584ull    // [512][512] bf16
#define O_WD2T  101711872ull    // [9][128][128] bf16 (t,o,c)
#define O_WD3T  102006784ull    // [25][128][128] bf16 (t,o,c)
#define O_WO2T  102825984ull    // [9][64][128] bf16 (t,o,c)
#define O_WO3T  102973440ull    // [25][64][128] bf16 (t,o,c)
// reuse of PXB region after b4 GEMM:
#define O_T2B   33554432ull     // [8][4096][128] bf16 b2i NHWC
#define O_T3B   41943040ull     // [8][4096][128] bf16 b3i NHWC
#define O_OFF2  50331648ull     // [8][18][4096] f32
#define O_OFF3  52690944ull     // [8][50][4096] f32

__device__ __forceinline__ unsigned short f2b(float f) {
    union { float f; unsigned u; } v; v.f = f;
    unsigned r = v.u + 0x7FFFu + ((v.u >> 16) & 1u);
    return (unsigned short)(r >> 16);
}
__device__ __forceinline__ float lou(unsigned u) {
    union { unsigned u; float f; } v; v.u = u << 16; return v.f;
}
__device__ __forceinline__ float hiu(unsigned u) {
    union { unsigned u; float f; } v; v.u = u & 0xFFFF0000u; return v.f;
}
__device__ __forceinline__ unsigned pk2(float lo, float hi) {
    return (unsigned)f2b(lo) | ((unsigned)f2b(hi) << 16);
}

// ------------------------------------------------------------- weight prep
__global__ __launch_bounds__(256) void k_prepw(
        const float* __restrict__ w1, const float* __restrict__ w21,
        const float* __restrict__ w31, const float* __restrict__ w4,
        const float* __restrict__ wcc, const float* __restrict__ wd2,
        const float* __restrict__ wd3, const float* __restrict__ wo2,
        const float* __restrict__ wo3, unsigned short* __restrict__ ws8) {
    unsigned i = blockIdx.x * 256 + threadIdx.x;
    unsigned short* wpb  = ws8 + (O_WPB  >> 1);
    unsigned short* w4b  = ws8 + (O_W4B  >> 1);
    unsigned short* wccb = ws8 + (O_WCCB >> 1);
    unsigned short* wd2t = ws8 + (O_WD2T >> 1);
    unsigned short* wd3t = ws8 + (O_WD3T >> 1);
    unsigned short* wo2t = ws8 + (O_WO2T >> 1);
    unsigned short* wo3t = ws8 + (O_WO3T >> 1);
    if (i < 196608) {
        int o = i >> 9;
        float v = (o < 128) ? w1[i] : (o < 256) ? w21[i - 65536] : w31[i - 131072];
        wpb[i] = f2b(v);
    } else if (i < 262144) {
        unsigned j = i - 196608; w4b[j] = f2b(w4[j]);
    } else if (i < 524288) {
        unsigned j = i - 262144; wccb[j] = f2b(wcc[j]);
    } else if (i < 671744) {
        unsigned j = i - 524288; int t = j >> 14, o = (j >> 7) & 127, c = j & 127;
        wd2t[j] = f2b(wd2[((o * 128 + c) * 9) + t]);
    } else if (i < 1081344) {
        unsigned j = i - 671744; int t = j >> 14, o = (j >> 7) & 127, c = j & 127;
        wd3t[j] = f2b(wd3[((o * 128 + c) * 25) + t]);
    } else if (i < 1155072) {
        // layout (t, o, c): j = (t*64 + o)*128 + c
        unsigned j = i - 1081344; int t = j >> 13, o = (j >> 7) & 63, c = j & 127;
        wo2t[j] = (o < 18) ? f2b(wo2[((o * 128 + c) * 9) + t]) : 0;
    } else if (i < 1359872) {
        unsigned j = i - 1155072; int t = j >> 13, o = (j >> 7) & 63, c = j & 127;
        wo3t[j] = (o < 50) ? f2b(wo3[((o * 128 + c) * 25) + t]) : 0;
    }
}

// ---------------------------------------- x NCHW f32 -> NHWC bf16 transpose
__global__ __launch_bounds__(256) void k_xpose(const float* __restrict__ X,
                                               unsigned short* __restrict__ xbT) {
    __shared__ unsigned short t[32][33];
    const int p0 = blockIdx.x * 32, c0 = blockIdx.y * 32, b = blockIdx.z;
    const int tid = threadIdx.x;
    #pragma unroll
    for (int s = 0; s < 4; ++s) {
        int cl = s * 8 + (tid >> 5), pl = tid & 31;
        t[cl][pl] = f2b(X[((size_t)b * 512 + c0 + cl) * HW + p0 + pl]);
    }
    __syncthreads();
    #pragma unroll
    for (int s = 0; s < 4; ++s) {
        int pl = s * 8 + (tid >> 5), cl = tid & 31;
        xbT[((size_t)b * HW + p0 + pl) * 512 + c0 + cl] = t[cl][pl];
    }
}

// ----------------------------------------------- 3x3 s1 maxpool on NHWC bf16
__global__ __launch_bounds__(256) void k_pool(const unsigned short* __restrict__ xbT,
                                              unsigned short* __restrict__ pxb) {
    unsigned gid = blockIdx.x * 256 + threadIdx.x;   // 8*4096*64
    int b = gid >> 18;
    unsigned rem = gid & 262143;
    int pos = rem >> 6;
    int cg = (rem & 63) * 8;
    int h = pos >> 6, w = pos & 63;
    const unsigned short* img = xbT + (size_t)b * HW * 512;
    float m[8] = {-INFINITY, -INFINITY, -INFINITY, -INFINITY,
                  -INFINITY, -INFINITY, -INFINITY, -INFINITY};
    #pragma unroll
    for (int dy = -1; dy <= 1; ++dy) {
        int hh = h + dy;
        if (hh < 0 || hh >= 64) continue;
        #pragma unroll
        for (int dx = -1; dx <= 1; ++dx) {
            int ww = w + dx;
            if (ww < 0 || ww >= 64) continue;
            uint4 v = *(const uint4*)(img + ((size_t)(hh * 64 + ww)) * 512 + cg);
            unsigned uu[4] = {v.x, v.y, v.z, v.w};
            #pragma unroll
            for (int e = 0; e < 4; ++e) {
                m[2 * e]     = fmaxf(m[2 * e],     lou(uu[e]));
                m[2 * e + 1] = fmaxf(m[2 * e + 1], hiu(uu[e]));
            }
        }
    }
    uint4 o;
    o.x = pk2(m[0], m[1]); o.y = pk2(m[2], m[3]);
    o.z = pk2(m[4], m[5]); o.w = pk2(m[6], m[7]);
    *(uint4*)(pxb + ((size_t)b * HW + pos) * 512 + cg) = o;
}

// ----------------------------- bf16 MFMA GEMM: C[128 x 128pos] = A[128x512]B
#define SA(r,c) SM[(r)*40 + (c)]
#define SB(r,c) SM[5120 + (r)*40 + (c)]
#define SC(r,c) SM[(r)*136 + (c)]
__global__ __launch_bounds__(256) void k_gemm(
        const unsigned short* __restrict__ A, const float* __restrict__ bias,
        const unsigned short* __restrict__ Bm,
        unsigned short* __restrict__ dst, int dStride, int dOff) {
    __shared__ unsigned short SM[17408];
    const int tid = threadIdx.x;
    const int n0 = blockIdx.x * 128;
    const int b = blockIdx.z;
    const int wave = tid >> 6, lane = tid & 63, quad = lane >> 4, lr = lane & 15;
    const int m0w = (wave & 1) * 64, n0w = (wave >> 1) * 64;
    const int srow = tid >> 1, skh = (tid & 1) * 16;
    floatx4 acc[4][4] = {};

    for (int k0 = 0; k0 < 512; k0 += 32) {
        const unsigned short* ga = A + (size_t)srow * 512 + k0 + skh;
        uint4 a0 = *(const uint4*)(ga);
        uint4 a1 = *(const uint4*)(ga + 8);
        const unsigned short* gb = Bm + ((size_t)b * HW + n0 + srow) * 512 + k0 + skh;
        uint4 b0 = *(const uint4*)(gb);
        uint4 b1 = *(const uint4*)(gb + 8);
        __syncthreads();
        *(uint4*)&SA(srow, skh) = a0;
        *(uint4*)&SA(srow, skh + 8) = a1;
        *(uint4*)&SB(srow, skh) = b0;
        *(uint4*)&SB(srow, skh + 8) = b1;
        __syncthreads();
        short8 af[4], bf[4];
        #pragma unroll
        for (int i = 0; i < 4; ++i) af[i] = *(short8*)&SA(m0w + i * 16 + lr, quad * 8);
        #pragma unroll
        for (int j = 0; j < 4; ++j) bf[j] = *(short8*)&SB(n0w + j * 16 + lr, quad * 8);
        #pragma unroll
        for (int i = 0; i < 4; ++i)
            #pragma unroll
            for (int j = 0; j < 4; ++j)
                acc[i][j] = __builtin_amdgcn_mfma_f32_16x16x32_bf16(af[i], bf[j], acc[i][j], 0, 0, 0);
    }
    __syncthreads();
    #pragma unroll
    for (int i = 0; i < 4; ++i) {
        float4 bs = *(const float4*)&bias[m0w + i * 16 + quad * 4];
        #pragma unroll
        for (int j = 0; j < 4; ++j) {
            floatx4 v = acc[i][j];
            int pos = n0w + j * 16 + lr;
            int ch = m0w + i * 16 + quad * 4;
            uint2 st;
            st.x = pk2(v[0] + bs.x, v[1] + bs.y);
            st.y = pk2(v[2] + bs.z, v[3] + bs.w);
            *(uint2*)&SC(pos, ch) = st;
        }
    }
    __syncthreads();
    #pragma unroll
    for (int r = 0; r < 8; ++r) {
        int pos = (tid >> 4) + r * 16;
        *(uint4*)&dst[((size_t)b * HW + n0 + pos) * dStride + dOff + (tid & 15) * 8] =
            *(uint4*)&SC(pos, (tid & 15) * 8);
    }
}

// ---------------- offset convs v2: slab-staged, barrier-free tap loop
// block = 128 positions (2 h-rows) x 64 M (padded), 512 threads.
template<int KS, int OCH>
__global__ __launch_bounds__(512) void k_offconv2(
        const unsigned short* __restrict__ img,   // [B][4096][128] bf16
        const unsigned short* __restrict__ woT,   // [TT][64][128] bf16 (t,o,c)
        const float* __restrict__ bias, float* __restrict__ Out) {
    constexpr int PAD = KS / 2;
    constexpr int TT = KS * KS;
    constexpr int SR = 2 + 2 * PAD;
    constexpr int SC2 = 64 + 2 * PAD;
    constexpr int NE = SR * SC2;              // slab entries
    __shared__ unsigned short slab[NE * 36];  // [entry][36] (32 ch + pad)
    __shared__ float ctile[64 * 132];
    const int tid = threadIdx.x;
    const int p0 = blockIdx.x * 128, hrow0 = blockIdx.x * 2, b = blockIdx.z;
    const int wave = tid >> 6, lane = tid & 63, quad = lane >> 4, lr = lane & 15;
    const int wm = wave & 1, wn = wave >> 1;   // 2 x 4 wave grid: 32o x 32pos
    const unsigned short* ib = img + (size_t)b * HW * 128;
    floatx4 acc[2][2] = {};

    for (int c0 = 0; c0 < 128; c0 += 32) {
        __syncthreads();
        if (tid < NE) {
            int s = tid / SC2, cl = tid % SC2;
            int r = hrow0 - PAD + s, cc = cl - PAD;
            uint4 v0 = {}, v1 = {}, v2 = {}, v3 = {};
            if ((unsigned)r < 64u && (unsigned)cc < 64u) {
                const uint4* g = (const uint4*)(ib + ((size_t)(r * 64 + cc)) * 128 + c0);
                v0 = g[0]; v1 = g[1]; v2 = g[2]; v3 = g[3];
            }
            uint2* d2 = (uint2*)&slab[tid * 36];
            d2[0] = make_uint2(v0.x, v0.y); d2[1] = make_uint2(v0.z, v0.w);
            d2[2] = make_uint2(v1.x, v1.y); d2[3] = make_uint2(v1.z, v1.w);
            d2[4] = make_uint2(v2.x, v2.y); d2[5] = make_uint2(v2.z, v2.w);
            d2[6] = make_uint2(v3.x, v3.y); d2[7] = make_uint2(v3.z, v3.w);
        }
        __syncthreads();
        #pragma unroll
        for (int t = 0; t < TT; ++t) {
            const int ky = t / KS, kx = t % KS;
            short8 af[2], bf[2];
            #pragma unroll
            for (int i = 0; i < 2; ++i)
                af[i] = *(const short8*)&woT[((size_t)t * 64 + wm * 32 + i * 16 + lr) * 128
                                             + c0 + quad * 8];
            #pragma unroll
            for (int j = 0; j < 2; ++j) {
                int p = wn * 32 + j * 16 + lr;
                int e = ((p >> 6) + ky) * SC2 + (p & 63) + kx;
                union { uint2 u[2]; short8 s; } bb;
                const uint2* sp = (const uint2*)&slab[e * 36 + quad * 8];
                bb.u[0] = sp[0]; bb.u[1] = sp[1];
                bf[j] = bb.s;
            }
            #pragma unroll
            for (int i = 0; i < 2; ++i)
                #pragma unroll
                for (int j = 0; j < 2; ++j)
                    acc[i][j] = __builtin_amdgcn_mfma_f32_16x16x32_bf16(af[i], bf[j], acc[i][j], 0, 0, 0);
        }
    }
    __syncthreads();
    #pragma unroll
    for (int i = 0; i < 2; ++i)
        #pragma unroll
        for (int j = 0; j < 2; ++j) {
            floatx4 v = acc[i][j];
            int p = wn * 32 + j * 16 + lr;
            int o = wm * 32 + i * 16 + quad * 4;
            #pragma unroll
            for (int rg = 0; rg < 4; ++rg)
                ctile[(o + rg) * 132 + p] = v[rg];
        }
    __syncthreads();
    {
        int o = tid >> 3, seg = tid & 7;
        if (o < OCH) {
            float bs = bias[o];
            const float* src = &ctile[o * 132 + seg * 16];
            float* dst = &Out[((size_t)b * OCH + o) * HW + p0 + seg * 16];
            #pragma unroll
            for (int q = 0; q < 4; ++q) {
                float4 v = *(const float4*)(src + q * 4);
                v.x += bs; v.y += bs; v.z += bs; v.w += bs;
                *(float4*)(dst + q * 4) = v;
            }
        }
    }
}

// ------------- deformable conv v10: 4-wave blocks, 4 independent blocks/CU
// block = 256 threads (4 waves), tile = 128 o x 32 pos, grid = (128,1,8)
// = 1024 blocks = 4/CU (LDS 17.4KB). Stall in one block's tap chain is
// covered by the other 3 independent barrier-groups on the CU.
// Weight loads hoisted BEFORE the barrier (L2 latency overlaps barrier wait).
// XCD-pinned batch (x&7) kept from v9 (FETCH 49.5->10.6MB proven).
#define DC_GATHER(T, DY, DX) do {                                              \
    float fy = (float)(h + (T) / KS - PAD) + (DY);                             \
    float fx = (float)(w + (T) % KS - PAD) + (DX);                             \
    float y0f = floorf(fy), x0f = floorf(fx);                                  \
    float wyv = fy - y0f, wxv = fx - x0f;                                      \
    int y0 = (int)y0f, x0 = (int)x0f;                                          \
    w00 = (1.f - wyv) * (1.f - wxv); w01 = (1.f - wyv) * wxv;                  \
    w10 = wyv * (1.f - wxv);         w11 = wyv * wxv;                          \
    bool yv0 = (unsigned)y0 < 64u, yv1 = (unsigned)(y0 + 1) < 64u;             \
    bool xv0 = (unsigned)x0 < 64u, xv1 = (unsigned)(x0 + 1) < 64u;             \
    long bidx = (long)(y0 * 64 + x0) * 128 + cseg;                             \
    cn0 = z4; cn1 = z4; cn2 = z4; cn3 = z4;                                    \
    cn4 = z4; cn5 = z4; cn6 = z4; cn7 = z4;                                    \
    if (yv0 && xv0) { const uint4* p_ = (const uint4*)(ib + bidx);             \
        cn0 = p_[0]; cn1 = p_[1]; }                                            \
    if (yv0 && xv1) { const uint4* p_ = (const uint4*)(ib + bidx + 128);       \
        cn2 = p_[0]; cn3 = p_[1]; }                                            \
    if (yv1 && xv0) { const uint4* p_ = (const uint4*)(ib + bidx + 8192);      \
        cn4 = p_[0]; cn5 = p_[1]; }                                            \
    if (yv1 && xv1) { const uint4* p_ = (const uint4*)(ib + bidx + 8320);      \
        cn6 = p_[0]; cn7 = p_[1]; }                                            \
} while (0)

// blend with v_cvt_pk_bf16_f32 (RNE, bit-identical to f2b emulation)
#define DC_BLEND(RA, RB, RC, RD, OUT) do {                                     \
    unsigned a_[4] = {RA.x, RA.y, RA.z, RA.w};                                 \
    unsigned b_[4] = {RB.x, RB.y, RB.z, RB.w};                                 \
    unsigned c_[4] = {RC.x, RC.y, RC.z, RC.w};                                 \
    unsigned d_[4] = {RD.x, RD.y, RD.z, RD.w};                                 \
    unsigned r_[4];                                                            \
    _Pragma("unroll")                                                          \
    for (int e_ = 0; e_ < 4; ++e_) {                                           \
        float lo_ = w00 * lou(a_[e_]) + w01 * lou(b_[e_])                      \
                  + w10 * lou(c_[e_]) + w11 * lou(d_[e_]);                     \
        float hi_ = w00 * hiu(a_[e_]) + w01 * hiu(b_[e_])                      \
                  + w10 * hiu(c_[e_]) + w11 * hiu(d_[e_]);                     \
        asm("v_cvt_pk_bf16_f32 %0, %1, %2"                                     \
            : "=v"(r_[e_]) : "v"(lo_), "v"(hi_));                              \
    }                                                                          \
    OUT.x = r_[0]; OUT.y = r_[1]; OUT.z = r_[2]; OUT.w = r_[3];                \
} while (0)

template<int KS>
__global__ __launch_bounds__(256, 4) void k_deform10(
        const unsigned short* __restrict__ img,   // [B][4096][128] bf16
        const float* __restrict__ Off,            // [B][2TT][4096] f32
        const unsigned short* __restrict__ wdT,   // [TT][128][128] bf16 (t,o,c)
        const float* __restrict__ bias,
        unsigned short* __restrict__ catb, int dOff) {
    constexpr int PAD = KS / 2;
    constexpr int TT = KS * KS;
    __shared__ unsigned short sS[2][32][136];  // samples [buf][pos][c], +8 pad
    const int tid = threadIdx.x;
    // XCD-pinned remap: all blocks of batch b land on XCD b (L%8 model)
    const int b = blockIdx.x & 7;
    const int tile = (blockIdx.x >> 3) + 16 * blockIdx.z;  // 0..127
    const int p0 = tile * 32;
    const int wave = tid >> 6, lane = tid & 63, quad = lane >> 4, lr = lane & 15;
    const int m0w = wave * 32;                 // 4 m-waves x 32 o, all share 32 pos
    const int pos = tid >> 3;                  // 0..31
    const int cseg = (tid & 7) * 16;           // 16-ch segment
    const int pglob = p0 + pos;
    const int h = pglob >> 6, w = pglob & 63;
    const unsigned short* ib = img + (size_t)b * HW * 128;
    const float* offb = Off + (size_t)b * 2 * TT * HW;
    const uint4 z4 = make_uint4(0u, 0u, 0u, 0u);

    floatx4 acc00 = {}, acc01 = {}, acc10 = {}, acc11 = {};
    uint4 cn0, cn1, cn2, cn3, cn4, cn5, cn6, cn7;   // corners (A,B,C,D)x2
    float w00, w01, w10, w11;
    float noy = 0.f, nox = 0.f;

    // prologue: gather tap 0; prefetch offsets for tap 1
    {
        float dy0 = offb[pglob];
        float dx0 = offb[HW + pglob];
        DC_GATHER(0, dy0, dx0);
    }
    if (TT > 1) { noy = offb[2 * HW + pglob]; nox = offb[3 * HW + pglob]; }

    for (int t = 0; t < TT; ++t) {
        const int cur = t & 1;
        // INTERP(t): blend corners -> 16 bf16 samples
        uint4 ov0, ov1;
        DC_BLEND(cn0, cn2, cn4, cn6, ov0);
        DC_BLEND(cn1, cn3, cn5, cn7, ov1);
        *(uint4*)&sS[cur][pos][cseg] = ov0;
        *(uint4*)&sS[cur][pos][cseg + 8] = ov1;
        // weights(t) -> named regs, issued BEFORE the barrier so their L2
        // latency overlaps the barrier rendezvous
        const unsigned short* wb = wdT + (size_t)t * 16384
                                   + (size_t)(m0w + lr) * 128 + quad * 8;
        short8 wr0 = *(const short8*)(wb);
        short8 wr1 = *(const short8*)(wb + 2048);        // row +16
        short8 wr2 = *(const short8*)(wb + 32);          // ks=1
        short8 wr3 = *(const short8*)(wb + 2080);
        short8 wr4 = *(const short8*)(wb + 64);          // ks=2
        short8 wr5 = *(const short8*)(wb + 2112);
        short8 wr6 = *(const short8*)(wb + 96);          // ks=3
        short8 wr7 = *(const short8*)(wb + 2144);
        __syncthreads();
        // issue gathers(t+1), prefetch offsets(t+2) — in flight through MFMA(t)
        if (t + 1 < TT) {
            DC_GATHER(t + 1, noy, nox);
            if (t + 2 < TT) {
                noy = offb[(size_t)(2 * t + 4) * HW + pglob];
                nox = offb[(size_t)(2 * t + 5) * HW + pglob];
            }
        }
        // MFMA(t): 128o x 32pos per block, 32o rows per wave
        #pragma unroll
        for (int ks = 0; ks < 4; ++ks) {
            short8 bf0 = *(short8*)&sS[cur][lr][ks * 32 + quad * 8];
            short8 bf1 = *(short8*)&sS[cur][16 + lr][ks * 32 + quad * 8];
            short8 a0 = (ks == 0) ? wr0 : (ks == 1) ? wr2 : (ks == 2) ? wr4 : wr6;
            short8 a1 = (ks == 0) ? wr1 : (ks == 1) ? wr3 : (ks == 2) ? wr5 : wr7;
            acc00 = __builtin_amdgcn_mfma_f32_16x16x32_bf16(a0, bf0, acc00, 0, 0, 0);
            acc01 = __builtin_amdgcn_mfma_f32_16x16x32_bf16(a0, bf1, acc01, 0, 0, 0);
            acc10 = __builtin_amdgcn_mfma_f32_16x16x32_bf16(a1, bf0, acc10, 0, 0, 0);
            acc11 = __builtin_amdgcn_mfma_f32_16x16x32_bf16(a1, bf1, acc11, 0, 0, 0);
        }
    }
    // epilogue: bias + bf16 pack via sS[0], coalesced store to catb
    __syncthreads();
    {
        float4 bs = *(const float4*)&bias[m0w + quad * 4];
        float4 bs2 = *(const float4*)&bias[m0w + 16 + quad * 4];
        floatx4 v;
        uint2 st;
        int ch0 = m0w + quad * 4, ch1 = m0w + 16 + quad * 4;
        v = acc00;
        st.x = pk2(v[0] + bs.x, v[1] + bs.y);
        st.y = pk2(v[2] + bs.z, v[3] + bs.w);
        *(uint2*)&sS[0][lr][ch0] = st;
        v = acc01;
        st.x = pk2(v[0] + bs.x, v[1] + bs.y);
        st.y = pk2(v[2] + bs.z, v[3] + bs.w);
        *(uint2*)&sS[0][16 + lr][ch0] = st;
        v = acc10;
        st.x = pk2(v[0] + bs2.x, v[1] + bs2.y);
        st.y = pk2(v[2] + bs2.z, v[3] + bs2.w);
        *(uint2*)&sS[0][lr][ch1] = st;
        v = acc11;
        st.x = pk2(v[0] + bs2.x, v[1] + bs2.y);
        st.y = pk2(v[2] + bs2.z, v[3] + bs2.w);
        *(uint2*)&sS[0][16 + lr][ch1] = st;
    }
    __syncthreads();
    #pragma unroll
    for (int r = 0; r < 2; ++r) {
        int idx = r * 256 + tid;
        int p = idx >> 4, sg = (idx & 15) * 8;
        *(uint4*)&catb[((size_t)b * HW + p0 + p) * 512 + dOff + sg] =
            *(uint4*)&sS[0][p][sg];
    }
}

// ------------------- final: sigmoid(Wcc @ (catb*xbT)) + x, fp32 NCHW output
__global__ __launch_bounds__(256) void k_gemm_final(
        const unsigned short* __restrict__ A, const float* __restrict__ bias,
        const unsigned short* __restrict__ catb, const unsigned short* __restrict__ xbT,
        const float* __restrict__ X, float* __restrict__ OutF) {
    __shared__ unsigned short sA[128][40];
    __shared__ unsigned short sB[128][40];
    const int tid = threadIdx.x;
    const int n0 = blockIdx.x * 128;
    const int o0 = blockIdx.y * 128;
    const int b = blockIdx.z;
    const int wave = tid >> 6, lane = tid & 63, quad = lane >> 4, lr = lane & 15;
    const int m0w = (wave & 1) * 64, n0w = (wave >> 1) * 64;
    const int srow = tid >> 1, skh = (tid & 1) * 16;
    floatx4 acc[4][4] = {};

    for (int k0 = 0; k0 < 512; k0 += 32) {
        const unsigned short* ga = A + (size_t)(o0 + srow) * 512 + k0 + skh;
        uint4 a0 = *(const uint4*)(ga);
        uint4 a1 = *(const uint4*)(ga + 8);
        size_t bi = ((size_t)b * HW + n0 + srow) * 512 + k0 + skh;
        uint4 c0 = *(const uint4*)(catb + bi);
        uint4 c1 = *(const uint4*)(catb + bi + 8);
        uint4 x0 = *(const uint4*)(xbT + bi);
        uint4 x1 = *(const uint4*)(xbT + bi + 8);
        unsigned cu[8] = {c0.x, c0.y, c0.z, c0.w, c1.x, c1.y, c1.z, c1.w};
        unsigned xu[8] = {x0.x, x0.y, x0.z, x0.w, x1.x, x1.y, x1.z, x1.w};
        unsigned mu[8];
        #pragma unroll
        for (int e = 0; e < 8; ++e)
            mu[e] = pk2(lou(cu[e]) * lou(xu[e]), hiu(cu[e]) * hiu(xu[e]));
        __syncthreads();
        *(uint4*)&sA[srow][skh] = a0;
        *(uint4*)&sA[srow][skh + 8] = a1;
        uint4 m0v; m0v.x = mu[0]; m0v.y = mu[1]; m0v.z = mu[2]; m0v.w = mu[3];
        uint4 m1v; m1v.x = mu[4]; m1v.y = mu[5]; m1v.z = mu[6]; m1v.w = mu[7];
        *(uint4*)&sB[srow][skh] = m0v;
        *(uint4*)&sB[srow][skh + 8] = m1v;
        __syncthreads();
        short8 af[4], bf[4];
        #pragma unroll
        for (int i = 0; i < 4; ++i) af[i] = *(short8*)&sA[m0w + i * 16 + lr][quad * 8];
        #pragma unroll
        for (int j = 0; j < 4; ++j) bf[j] = *(short8*)&sB[n0w + j * 16 + lr][quad * 8];
        #pragma unroll
        for (int i = 0; i < 4; ++i)
            #pragma unroll
            for (int j = 0; j < 4; ++j)
                acc[i][j] = __builtin_amdgcn_mfma_f32_16x16x32_bf16(af[i], bf[j], acc[i][j], 0, 0, 0);
    }
    #pragma unroll
    for (int i = 0; i < 4; ++i) {
        float4 bs = *(const float4*)&bias[o0 + m0w + i * 16 + quad * 4];
        float bsa[4] = {bs.x, bs.y, bs.z, bs.w};
        #pragma unroll
        for (int j = 0; j < 4; ++j) {
            floatx4 v = acc[i][j];
            int pos = n0 + n0w + j * 16 + lr;
            #pragma unroll
            for (int rg = 0; rg < 4; ++rg) {
                int o = o0 + m0w + i * 16 + quad * 4 + rg;
                float f = v[rg] + bsa[rg];
                float sg = 1.f / (1.f + __expf(-f));
                size_t idx = ((size_t)b * 512 + o) * HW + pos;
                OutF[idx] = X[idx] + sg;
            }
        }
    }
}

// ------------------------------------------------------------------- launcher
extern "C" void kernel_launch(void* const* d_in, const int* in_sizes, int n_in,
                              void* d_out, int out_size, void* d_ws, size_t ws_size,
                              hipStream_t stream) {
    const float* x      = (const float*)d_in[0];
    const float* w_b1   = (const float*)d_in[1];
    const float* b_b1   = (const float*)d_in[2];
    const float* w_b21  = (const float*)d_in[3];
    const float* b_b21  = (const float*)d_in[4];
    const float* w_off2 = (const float*)d_in[5];
    const float* b_off2 = (const float*)d_in[6];
    const float* w_ddc2 = (const float*)d_in[7];
    const float* b_ddc2 = (const float*)d_in[8];
    const float* w_b31  = (const float*)d_in[9];
    const float* b_b31  = (const float*)d_in[10];
    const float* w_off3 = (const float*)d_in[11];
    const float* b_off3 = (const float*)d_in[12];
    const float* w_ddc3 = (const float*)d_in[13];
    const float* b_ddc3 = (const float*)d_in[14];
    const float* w_b4   = (const float*)d_in[15];
    const float* b_b4   = (const float*)d_in[16];
    const float* w_cc   = (const float*)d_in[17];
    const float* b_cc   = (const float*)d_in[18];

    char* wsb = (char*)d_ws;
    unsigned short* ws8  = (unsigned short*)d_ws;
    unsigned short* xbT  = (unsigned short*)(wsb + O_XBT);
    unsigned short* pxb  = (unsigned short*)(wsb + O_PXB);
    unsigned short* catb = (unsigned short*)(wsb + O_CATB);
    unsigned short* wpb  = (unsigned short*)(wsb + O_WPB);
    unsigned short* w4b  = (unsigned short*)(wsb + O_W4B);
    unsigned short* wccb = (unsigned short*)(wsb + O_WCCB);
    unsigned short* wd2t = (unsigned short*)(wsb + O_WD2T);
    unsigned short* wd3t = (unsigned short*)(wsb + O_WD3T);
    unsigned short* wo2t = (unsigned short*)(wsb + O_WO2T);
    unsigned short* wo3t = (unsigned short*)(wsb + O_WO3T);
    unsigned short* t2b  = (unsigned short*)(wsb + O_T2B);
    unsigned short* t3b  = (unsigned short*)(wsb + O_T3B);
    float* off2 = (float*)(wsb + O_OFF2);
    float* off3 = (float*)(wsb + O_OFF3);
    float* out  = (float*)d_out;

    k_prepw<<<dim3(5312), dim3(256), 0, stream>>>(
        w_b1, w_b21, w_b31, w_b4, w_cc, w_ddc2, w_ddc3, w_off2, w_off3, ws8);
    k_xpose<<<dim3(128, 16, 8), dim3(256), 0, stream>>>(x, xbT);
    k_pool<<<dim3(8192), dim3(256), 0, stream>>>(xbT, pxb);
    // b4 first (frees pxb region for t2b/t3b/offsets)
    k_gemm<<<dim3(32, 1, 8), dim3(256), 0, stream>>>(w4b, b_b4, pxb, catb, 512, 384);
    k_gemm<<<dim3(32, 1, 8), dim3(256), 0, stream>>>(wpb, b_b1, xbT, catb, 512, 0);
    k_gemm<<<dim3(32, 1, 8), dim3(256), 0, stream>>>(wpb + 128 * 512, b_b21, xbT, t2b, 128, 0);
    k_gemm<<<dim3(32, 1, 8), dim3(256), 0, stream>>>(wpb + 256 * 512, b_b31, xbT, t3b, 128, 0);
    k_offconv2<3, 18><<<dim3(32, 1, 8), dim3(512), 0, stream>>>(t2b, wo2t, b_off2, off2);
    k_offconv2<5, 50><<<dim3(32, 1, 8), dim3(512), 0, stream>>>(t3b, wo3t, b_off3, off3);
    k_deform10<3><<<dim3(128, 1, 8), dim3(256), 0, stream>>>(t2b, off2, wd2t, b_ddc2, catb, 128);
    k_deform10<5><<<dim3(128, 1, 8), dim3(256), 0, stream>>>(t3b, off3, wd3t, b_ddc3, catb, 256);
    k_gemm_final<<<dim3(32, 4, 8), dim3(256), 0, stream>>>(wccb, b_cc, catb, xbT, x, out);
}